// Round 1
// baseline (3026.786 us; speedup 1.0000x reference)
//
#include <hip/hip_runtime.h>

#define BB   4
#define CC   256
#define NPIX 4096
#define KT   16

// ---------------------------------------------------------------------------
// 128x128-tile NN GEMM body, K=256 fixed, lda=256, ldb=ldOut=4096.
// Out[tm0..+127, tn0..+127] = A * B (+ bias[row] if bias != nullptr)
// block = 256 threads, 8x8 micro-tile per thread.
// ---------------------------------------------------------------------------
__device__ __forceinline__ void gemm128_nn_k256(
    const float* __restrict__ A, const float* __restrict__ Bm,
    const float* __restrict__ bias, float* __restrict__ Out,
    int tm0, int tn0)
{
    __shared__ float AsT[KT][132];   // [k][m], padded
    __shared__ float Bs[KT][132];    // [k][n], padded
    const int t  = threadIdx.x;
    const int ty = t >> 4;           // row group (8 rows each)
    const int tx = t & 15;           // col group (8 cols each)

    float acc[8][8];
#pragma unroll
    for (int i = 0; i < 8; i++)
#pragma unroll
        for (int j = 0; j < 8; j++) acc[i][j] = 0.0f;

    for (int k0 = 0; k0 < 256; k0 += KT) {
        // A tile: 128 rows x KT -> transposed into LDS
#pragma unroll
        for (int L = t; L < 512; L += 256) {
            int row = L >> 2, kq = L & 3;
            float4 v = *(const float4*)(A + (size_t)(tm0 + row) * 256 + k0 + kq * 4);
            AsT[kq * 4 + 0][row] = v.x;
            AsT[kq * 4 + 1][row] = v.y;
            AsT[kq * 4 + 2][row] = v.z;
            AsT[kq * 4 + 3][row] = v.w;
        }
        // B tile: KT rows x 128
#pragma unroll
        for (int L = t; L < 512; L += 256) {
            int kr = L >> 5, nq = L & 31;
            float4 v = *(const float4*)(Bm + (size_t)(k0 + kr) * NPIX + tn0 + nq * 4);
            *(float4*)&Bs[kr][nq * 4] = v;
        }
        __syncthreads();
#pragma unroll
        for (int kk = 0; kk < KT; kk++) {
            float a[8], b[8];
            *(float4*)&a[0] = *(const float4*)&AsT[kk][ty * 8];
            *(float4*)&a[4] = *(const float4*)&AsT[kk][ty * 8 + 4];
            *(float4*)&b[0] = *(const float4*)&Bs[kk][tx * 8];
            *(float4*)&b[4] = *(const float4*)&Bs[kk][tx * 8 + 4];
#pragma unroll
            for (int i = 0; i < 8; i++)
#pragma unroll
                for (int j = 0; j < 8; j++)
                    acc[i][j] = fmaf(a[i], b[j], acc[i][j]);
        }
        __syncthreads();
    }

#pragma unroll
    for (int i = 0; i < 8; i++) {
        int row = tm0 + ty * 8 + i;
        float bval = bias ? bias[row] : 0.0f;
        float4 o0, o1;
        o0.x = acc[i][0] + bval; o0.y = acc[i][1] + bval;
        o0.z = acc[i][2] + bval; o0.w = acc[i][3] + bval;
        o1.x = acc[i][4] + bval; o1.y = acc[i][5] + bval;
        o1.z = acc[i][6] + bval; o1.w = acc[i][7] + bval;
        float* orow = Out + (size_t)row * NPIX + tn0 + tx * 8;
        *(float4*)orow = o0;
        *(float4*)(orow + 4) = o1;
    }
}

// Projections x1/x2/x3 for all batches: z = p*4 + b
__global__ __launch_bounds__(256) void proj_kernel(
    const float* __restrict__ x,
    const float* __restrict__ w0, const float* __restrict__ bi0,
    const float* __restrict__ w1, const float* __restrict__ bi1,
    const float* __restrict__ w2, const float* __restrict__ bi2,
    float* __restrict__ o0, float* __restrict__ o1, float* __restrict__ o2)
{
    int z = blockIdx.z;
    int p = z >> 2, b = z & 3;
    const float* W    = (p == 0) ? w0  : (p == 1) ? w1  : w2;
    const float* bias = (p == 0) ? bi0 : (p == 1) ? bi1 : bi2;
    float*       O    = (p == 0) ? o0  : (p == 1) ? o1  : o2;
    size_t off = (size_t)b * CC * NPIX;
    gemm128_nn_k256(W, x + off, bias, O + off, blockIdx.y * 128, blockIdx.x * 128);
}

// S = A1(view [N,C]) @ X2([C,N]) for one batch
__global__ __launch_bounds__(256) void scores_kernel(
    const float* __restrict__ x1b, const float* __restrict__ x2b, float* __restrict__ S)
{
    gemm128_nn_k256(x1b, x2b, nullptr, S, blockIdx.y * 128, blockIdx.x * 128);
}

// Row softmax stats: one block per row
__global__ __launch_bounds__(256) void rowstats_kernel(
    const float* __restrict__ S, float* __restrict__ rowm, float* __restrict__ rowli)
{
    int n = blockIdx.x;
    const float* r = S + (size_t)n * NPIX;
    int t = threadIdx.x;
    float m = -1e30f, l = 0.0f;
    for (int i = t; i < NPIX; i += 256) {
        float v = r[i];
        float mn = fmaxf(m, v);
        l = l * __expf(m - mn) + __expf(v - mn);
        m = mn;
    }
    for (int off = 32; off; off >>= 1) {
        float m2 = __shfl_xor(m, off, 64);
        float l2 = __shfl_xor(l, off, 64);
        float mn = fmaxf(m, m2);
        l = l * __expf(m - mn) + l2 * __expf(m2 - mn);
        m = mn;
    }
    __shared__ float sm[4], sl[4];
    int w = t >> 6;
    if ((t & 63) == 0) { sm[w] = m; sl[w] = l; }
    __syncthreads();
    if (t == 0) {
        m = sm[0]; l = sl[0];
        for (int i = 1; i < 4; i++) {
            float mn = fmaxf(m, sm[i]);
            l = l * __expf(m - mn) + sl[i] * __expf(sm[i] - mn);
            m = mn;
        }
        rowm[n]  = m;
        rowli[n] = 1.0f / l;
    }
}

// Column softmax stats, pass 1: partials per 128-row chunk
__global__ __launch_bounds__(256) void colstats1_kernel(
    const float* __restrict__ S, float* __restrict__ pm, float* __restrict__ pl)
{
    int col = blockIdx.x * 256 + threadIdx.x;
    int r0  = blockIdx.y * 128;
    float m = -1e30f, l = 0.0f;
    for (int r = 0; r < 128; r++) {
        float v = S[(size_t)(r0 + r) * NPIX + col];
        float mn = fmaxf(m, v);
        l = l * __expf(m - mn) + __expf(v - mn);
        m = mn;
    }
    pm[(size_t)blockIdx.y * NPIX + col] = m;
    pl[(size_t)blockIdx.y * NPIX + col] = l;
}

// Column softmax stats, pass 2: combine 32 partials
__global__ __launch_bounds__(256) void colstats2_kernel(
    const float* __restrict__ pm, const float* __restrict__ pl,
    float* __restrict__ cm, float* __restrict__ cli)
{
    int col = blockIdx.x * 256 + threadIdx.x;
    float m = -1e30f, l = 0.0f;
    for (int i = 0; i < 32; i++) {
        float m2 = pm[(size_t)i * NPIX + col];
        float l2 = pl[(size_t)i * NPIX + col];
        float mn = fmaxf(m, m2);
        l = l * __expf(m - mn) + l2 * __expf(m2 - mn);
        m = mn;
    }
    cm[col]  = m;
    cli[col] = 1.0f / l;
}

// Y = softmax(S) @ V  (mode 0: row softmax -> Y1, mode 1: col softmax -> Y2)
// tile: 64 rows x 256 cols, K over m in chunks of 16
__global__ __launch_bounds__(256) void ysoft_kernel(
    const float* __restrict__ S, const float* __restrict__ V,
    const float* __restrict__ rowm, const float* __restrict__ rowli,
    const float* __restrict__ colm, const float* __restrict__ colli,
    float* __restrict__ Y1, float* __restrict__ Y2)
{
    __shared__ float PsT[KT][68];     // [k][n]
    __shared__ float Vs[KT][260];     // [k][c]
    const int mode = blockIdx.y;
    const int n0 = blockIdx.x * 64;
    const int t = threadIdx.x;
    const int tx = t & 31;            // col group (8 cols)
    const int ty = t >> 5;            // row group (8 rows)

    float acc[8][8];
#pragma unroll
    for (int i = 0; i < 8; i++)
#pragma unroll
        for (int j = 0; j < 8; j++) acc[i][j] = 0.0f;

    for (int m0 = 0; m0 < NPIX; m0 += KT) {
        {   // S tile 64 x 16 -> P
            int row = t >> 2, kq = t & 3;
            float4 s4 = *(const float4*)(S + (size_t)(n0 + row) * NPIX + m0 + kq * 4);
            float p0, p1, p2, p3;
            if (mode == 0) {
                float mm = rowm[n0 + row], li = rowli[n0 + row];
                p0 = __expf(s4.x - mm) * li;
                p1 = __expf(s4.y - mm) * li;
                p2 = __expf(s4.z - mm) * li;
                p3 = __expf(s4.w - mm) * li;
            } else {
                int mb = m0 + kq * 4;
                p0 = __expf(s4.x - colm[mb + 0]) * colli[mb + 0];
                p1 = __expf(s4.y - colm[mb + 1]) * colli[mb + 1];
                p2 = __expf(s4.z - colm[mb + 2]) * colli[mb + 2];
                p3 = __expf(s4.w - colm[mb + 3]) * colli[mb + 3];
            }
            PsT[kq * 4 + 0][row] = p0;
            PsT[kq * 4 + 1][row] = p1;
            PsT[kq * 4 + 2][row] = p2;
            PsT[kq * 4 + 3][row] = p3;
        }
        // V tile 16 x 256
#pragma unroll
        for (int i = 0; i < 4; i++) {
            int L = t + i * 256;
            int mr = L >> 6, cq = L & 63;
            float4 v = *(const float4*)(V + (size_t)(m0 + mr) * CC + cq * 4);
            *(float4*)&Vs[mr][cq * 4] = v;
        }
        __syncthreads();
#pragma unroll
        for (int kk = 0; kk < KT; kk++) {
            float a[8], b[8];
            *(float4*)&a[0] = *(const float4*)&PsT[kk][ty * 8];
            *(float4*)&a[4] = *(const float4*)&PsT[kk][ty * 8 + 4];
            *(float4*)&b[0] = *(const float4*)&Vs[kk][tx * 8];
            *(float4*)&b[4] = *(const float4*)&Vs[kk][tx * 8 + 4];
#pragma unroll
            for (int i = 0; i < 8; i++)
#pragma unroll
                for (int j = 0; j < 8; j++)
                    acc[i][j] = fmaf(a[i], b[j], acc[i][j]);
        }
        __syncthreads();
    }

    float* Y = (mode == 0) ? Y1 : Y2;
#pragma unroll
    for (int i = 0; i < 8; i++) {
        int row = n0 + ty * 8 + i;
        float4 o0, o1;
        o0.x = acc[i][0]; o0.y = acc[i][1]; o0.z = acc[i][2]; o0.w = acc[i][3];
        o1.x = acc[i][4]; o1.y = acc[i][5]; o1.z = acc[i][6]; o1.w = acc[i][7];
        float* yr = Y + (size_t)row * CC + tx * 8;
        *(float4*)yr = o0;
        *(float4*)(yr + 4) = o1;
    }
}

// Final: out[b][ch][pix] = relu(x[b][ch&255][pix] + bias[ch] + sum_c W[ch][c]*Y[b][pix][c])
// NT GEMM 128x128 tiles; grid (pixtiles=32, chtiles=4, b=4)
__global__ __launch_bounds__(256) void out_kernel(
    const float* __restrict__ w_o1, const float* __restrict__ b_o1,
    const float* __restrict__ w_o2, const float* __restrict__ b_o2,
    const float* __restrict__ Y1, const float* __restrict__ Y2,
    const float* __restrict__ x, float* __restrict__ out)
{
    __shared__ float AsT[KT][132];    // [k][ch]
    __shared__ float BsT[KT][132];    // [k][pix]
    const int b    = blockIdx.z;
    const int ch0  = blockIdx.y * 128;          // 0..511
    const int pix0 = blockIdx.x * 128;
    const float* W    = (ch0 < 256) ? w_o1 : w_o2;
    const float* bias = (ch0 < 256) ? b_o1 : b_o2;
    const float* Y    = ((ch0 < 256) ? Y1 : Y2) + (size_t)b * NPIX * CC;
    const int chW0 = ch0 & 255;

    const int t  = threadIdx.x;
    const int ty = t >> 4;            // ch group
    const int tx = t & 15;            // pix group

    float acc[8][8];
#pragma unroll
    for (int i = 0; i < 8; i++)
#pragma unroll
        for (int j = 0; j < 8; j++) acc[i][j] = 0.0f;

    for (int k0 = 0; k0 < 256; k0 += KT) {
#pragma unroll
        for (int L = t; L < 512; L += 256) {
            int row = L >> 2, kq = L & 3;
            float4 v = *(const float4*)(W + (size_t)(chW0 + row) * 256 + k0 + kq * 4);
            AsT[kq * 4 + 0][row] = v.x;
            AsT[kq * 4 + 1][row] = v.y;
            AsT[kq * 4 + 2][row] = v.z;
            AsT[kq * 4 + 3][row] = v.w;
        }
#pragma unroll
        for (int L = t; L < 512; L += 256) {
            int row = L >> 2, kq = L & 3;
            float4 v = *(const float4*)(Y + (size_t)(pix0 + row) * 256 + k0 + kq * 4);
            BsT[kq * 4 + 0][row] = v.x;
            BsT[kq * 4 + 1][row] = v.y;
            BsT[kq * 4 + 2][row] = v.z;
            BsT[kq * 4 + 3][row] = v.w;
        }
        __syncthreads();
#pragma unroll
        for (int kk = 0; kk < KT; kk++) {
            float a[8], bb[8];
            *(float4*)&a[0]  = *(const float4*)&AsT[kk][ty * 8];
            *(float4*)&a[4]  = *(const float4*)&AsT[kk][ty * 8 + 4];
            *(float4*)&bb[0] = *(const float4*)&BsT[kk][tx * 8];
            *(float4*)&bb[4] = *(const float4*)&BsT[kk][tx * 8 + 4];
#pragma unroll
            for (int i = 0; i < 8; i++)
#pragma unroll
                for (int j = 0; j < 8; j++)
                    acc[i][j] = fmaf(a[i], bb[j], acc[i][j]);
        }
        __syncthreads();
    }

#pragma unroll
    for (int i = 0; i < 8; i++) {
        int ch = ch0 + ty * 8 + i;
        float bval = bias[ch & 255];
        const float* xr = x + ((size_t)b * CC + (ch & 255)) * NPIX + pix0 + tx * 8;
        float4 xa = *(const float4*)xr;
        float4 xb = *(const float4*)(xr + 4);
        float4 r0, r1;
        r0.x = fmaxf(acc[i][0] + bval + xa.x, 0.0f);
        r0.y = fmaxf(acc[i][1] + bval + xa.y, 0.0f);
        r0.z = fmaxf(acc[i][2] + bval + xa.z, 0.0f);
        r0.w = fmaxf(acc[i][3] + bval + xa.w, 0.0f);
        r1.x = fmaxf(acc[i][4] + bval + xb.x, 0.0f);
        r1.y = fmaxf(acc[i][5] + bval + xb.y, 0.0f);
        r1.z = fmaxf(acc[i][6] + bval + xb.z, 0.0f);
        r1.w = fmaxf(acc[i][7] + bval + xb.w, 0.0f);
        float* orow = out + ((size_t)b * 2 * CC + ch) * NPIX + pix0 + tx * 8;
        *(float4*)orow = r0;
        *(float4*)(orow + 4) = r1;
    }
}

extern "C" void kernel_launch(void* const* d_in, const int* in_sizes, int n_in,
                              void* d_out, int out_size, void* d_ws, size_t ws_size,
                              hipStream_t stream)
{
    (void)in_sizes; (void)n_in; (void)out_size; (void)ws_size;
    const float* x      = (const float*)d_in[0];
    const float* w_teta = (const float*)d_in[1];
    const float* b_teta = (const float*)d_in[2];
    const float* w_fi   = (const float*)d_in[3];
    const float* b_fi   = (const float*)d_in[4];
    const float* w_gi   = (const float*)d_in[5];
    const float* b_gi   = (const float*)d_in[6];
    const float* w_o1   = (const float*)d_in[7];
    const float* b_o1   = (const float*)d_in[8];
    const float* w_o2   = (const float*)d_in[9];
    const float* b_o2   = (const float*)d_in[10];
    float* out = (float*)d_out;

    // workspace layout (floats): ~36.3M floats = ~145 MB
    float* ws = (float*)d_ws;
    const size_t CN = (size_t)CC * NPIX;       // 1M
    float* x1    = ws;                         // BB*CN
    float* x2    = x1 + BB * CN;
    float* x3    = x2 + BB * CN;
    float* Y1    = x3 + BB * CN;
    float* Y2    = Y1 + BB * CN;
    float* S     = Y2 + BB * CN;               // NPIX*NPIX
    float* rowm  = S + (size_t)NPIX * NPIX;
    float* rowli = rowm + NPIX;
    float* cm    = rowli + NPIX;
    float* cli   = cm + NPIX;
    float* pm    = cli + NPIX;                 // 32*NPIX
    float* pl    = pm + 32 * NPIX;

    dim3 blk(256);
    proj_kernel<<<dim3(32, 2, 12), blk, 0, stream>>>(
        x, w_teta, b_teta, w_fi, b_fi, w_gi, b_gi, x1, x2, x3);

    for (int b = 0; b < BB; b++) {
        scores_kernel<<<dim3(32, 32), blk, 0, stream>>>(x1 + b * CN, x2 + b * CN, S);
        rowstats_kernel<<<dim3(NPIX), blk, 0, stream>>>(S, rowm, rowli);
        colstats1_kernel<<<dim3(16, 32), blk, 0, stream>>>(S, pm, pl);
        colstats2_kernel<<<dim3(16), blk, 0, stream>>>(pm, pl, cm, cli);
        ysoft_kernel<<<dim3(64, 2), blk, 0, stream>>>(
            S, x3 + b * CN, rowm, rowli, cm, cli, Y1 + b * CN, Y2 + b * CN);
    }

    out_kernel<<<dim3(32, 4, 4), blk, 0, stream>>>(
        w_o1, b_o1, w_o2, b_o2, Y1, Y2, x, out);
}

// Round 2
// 2017.529 us; speedup vs baseline: 1.5002x; 1.5002x over previous
//
#include <hip/hip_runtime.h>

#define BB   4
#define CC   256
#define NPIX 4096
#define KT   16
#define YKT  32

// ---------------------------------------------------------------------------
// 128x128-tile NN GEMM body, K=256 fixed, lda=256, ldb=ldOut=4096.
// Out[tm0..+127, tn0..+127] = A * B (+ bias[row] if bias != nullptr)
// block = 256 threads, 8x8 micro-tile per thread.
// Columns per thread: tn0 + tx*4 .. +3  and  tn0 + 64 + tx*4 .. +3
// (split-column mapping keeps LDS B-reads at <=2 addresses/bank = free)
// ---------------------------------------------------------------------------
__device__ __forceinline__ void gemm128_nn_k256(
    const float* __restrict__ A, const float* __restrict__ Bm,
    const float* __restrict__ bias, float* __restrict__ Out,
    int tm0, int tn0)
{
    __shared__ float AsT[KT][132];   // [k][m], padded
    __shared__ float Bs[KT][132];    // [k][n], padded
    const int t  = threadIdx.x;
    const int ty = t >> 4;           // row group (8 rows each)
    const int tx = t & 15;           // col group (4+4 cols, split by 64)

    float acc[8][8];
#pragma unroll
    for (int i = 0; i < 8; i++)
#pragma unroll
        for (int j = 0; j < 8; j++) acc[i][j] = 0.0f;

    for (int k0 = 0; k0 < 256; k0 += KT) {
        // A tile: 128 rows x KT -> transposed into LDS
#pragma unroll
        for (int L = t; L < 512; L += 256) {
            int row = L >> 2, kq = L & 3;
            float4 v = *(const float4*)(A + (size_t)(tm0 + row) * 256 + k0 + kq * 4);
            AsT[kq * 4 + 0][row] = v.x;
            AsT[kq * 4 + 1][row] = v.y;
            AsT[kq * 4 + 2][row] = v.z;
            AsT[kq * 4 + 3][row] = v.w;
        }
        // B tile: KT rows x 128
#pragma unroll
        for (int L = t; L < 512; L += 256) {
            int kr = L >> 5, nq = L & 31;
            float4 v = *(const float4*)(Bm + (size_t)(k0 + kr) * NPIX + tn0 + nq * 4);
            *(float4*)&Bs[kr][nq * 4] = v;
        }
        __syncthreads();
#pragma unroll
        for (int kk = 0; kk < KT; kk++) {
            float a[8], b[8];
            *(float4*)&a[0] = *(const float4*)&AsT[kk][ty * 8];
            *(float4*)&a[4] = *(const float4*)&AsT[kk][ty * 8 + 4];
            *(float4*)&b[0] = *(const float4*)&Bs[kk][tx * 4];
            *(float4*)&b[4] = *(const float4*)&Bs[kk][64 + tx * 4];
#pragma unroll
            for (int i = 0; i < 8; i++)
#pragma unroll
                for (int j = 0; j < 8; j++)
                    acc[i][j] = fmaf(a[i], b[j], acc[i][j]);
        }
        __syncthreads();
    }

#pragma unroll
    for (int i = 0; i < 8; i++) {
        int row = tm0 + ty * 8 + i;
        float bval = bias ? bias[row] : 0.0f;
        float4 o0, o1;
        o0.x = acc[i][0] + bval; o0.y = acc[i][1] + bval;
        o0.z = acc[i][2] + bval; o0.w = acc[i][3] + bval;
        o1.x = acc[i][4] + bval; o1.y = acc[i][5] + bval;
        o1.z = acc[i][6] + bval; o1.w = acc[i][7] + bval;
        float* orow = Out + (size_t)row * NPIX + tn0 + tx * 4;
        *(float4*)orow = o0;
        *(float4*)(orow + 64) = o1;
    }
}

// Projections x1/x2/x3 for all batches: z = p*4 + b
__global__ __launch_bounds__(256) void proj_kernel(
    const float* __restrict__ x,
    const float* __restrict__ w0, const float* __restrict__ bi0,
    const float* __restrict__ w1, const float* __restrict__ bi1,
    const float* __restrict__ w2, const float* __restrict__ bi2,
    float* __restrict__ o0, float* __restrict__ o1, float* __restrict__ o2)
{
    int z = blockIdx.z;
    int p = z >> 2, b = z & 3;
    const float* W    = (p == 0) ? w0  : (p == 1) ? w1  : w2;
    const float* bias = (p == 0) ? bi0 : (p == 1) ? bi1 : bi2;
    float*       O    = (p == 0) ? o0  : (p == 1) ? o1  : o2;
    size_t off = (size_t)b * CC * NPIX;
    gemm128_nn_k256(W, x + off, bias, O + off, blockIdx.y * 128, blockIdx.x * 128);
}

// S = A1(view [N,C]) @ X2([C,N]) for one batch
__global__ __launch_bounds__(256) void scores_kernel(
    const float* __restrict__ x1b, const float* __restrict__ x2b, float* __restrict__ S)
{
    gemm128_nn_k256(x1b, x2b, nullptr, S, blockIdx.y * 128, blockIdx.x * 128);
}

// Row softmax stats: one block per row
__global__ __launch_bounds__(256) void rowstats_kernel(
    const float* __restrict__ S, float* __restrict__ rowm, float* __restrict__ rowli)
{
    int n = blockIdx.x;
    const float* r = S + (size_t)n * NPIX;
    int t = threadIdx.x;
    float m = -1e30f, l = 0.0f;
    for (int i = t; i < NPIX; i += 256) {
        float v = r[i];
        float mn = fmaxf(m, v);
        l = l * __expf(m - mn) + __expf(v - mn);
        m = mn;
    }
    for (int off = 32; off; off >>= 1) {
        float m2 = __shfl_xor(m, off, 64);
        float l2 = __shfl_xor(l, off, 64);
        float mn = fmaxf(m, m2);
        l = l * __expf(m - mn) + l2 * __expf(m2 - mn);
        m = mn;
    }
    __shared__ float sm[4], sl[4];
    int w = t >> 6;
    if ((t & 63) == 0) { sm[w] = m; sl[w] = l; }
    __syncthreads();
    if (t == 0) {
        m = sm[0]; l = sl[0];
        for (int i = 1; i < 4; i++) {
            float mn = fmaxf(m, sm[i]);
            l = l * __expf(m - mn) + sl[i] * __expf(sm[i] - mn);
            m = mn;
        }
        rowm[n]  = m;
        rowli[n] = 1.0f / l;
    }
}

// Column softmax stats, pass 1: partials per 128-row chunk
__global__ __launch_bounds__(256) void colstats1_kernel(
    const float* __restrict__ S, float* __restrict__ pm, float* __restrict__ pl)
{
    int col = blockIdx.x * 256 + threadIdx.x;
    int r0  = blockIdx.y * 128;
    float m = -1e30f, l = 0.0f;
    for (int r = 0; r < 128; r++) {
        float v = S[(size_t)(r0 + r) * NPIX + col];
        float mn = fmaxf(m, v);
        l = l * __expf(m - mn) + __expf(v - mn);
        m = mn;
    }
    pm[(size_t)blockIdx.y * NPIX + col] = m;
    pl[(size_t)blockIdx.y * NPIX + col] = l;
}

// Column softmax stats, pass 2: combine 32 partials
__global__ __launch_bounds__(256) void colstats2_kernel(
    const float* __restrict__ pm, const float* __restrict__ pl,
    float* __restrict__ cm, float* __restrict__ cli)
{
    int col = blockIdx.x * 256 + threadIdx.x;
    float m = -1e30f, l = 0.0f;
    for (int i = 0; i < 32; i++) {
        float m2 = pm[(size_t)i * NPIX + col];
        float l2 = pl[(size_t)i * NPIX + col];
        float mn = fmaxf(m, m2);
        l = l * __expf(m - mn) + l2 * __expf(m2 - mn);
        m = mn;
    }
    cm[col]  = m;
    cli[col] = 1.0f / l;
}

// Y = softmax(S) @ V, one mode per block.
// tile: 64 rows(n) x 64 cols(c), K over m in chunks of YKT=32.
// grid: (c-tiles=4, n-tiles=64, mode=2) = 512 blocks, 256 threads.
// micro-tile 4x4 per thread. LDS B-reads at tx*4 (tx 0..15) = conflict-free.
__global__ __launch_bounds__(256) void ysoft_kernel(
    const float* __restrict__ S, const float* __restrict__ V,
    const float* __restrict__ rowm, const float* __restrict__ rowli,
    const float* __restrict__ colm, const float* __restrict__ colli,
    float* __restrict__ Y1, float* __restrict__ Y2)
{
    __shared__ float PT[YKT][65];     // [m][n] (stride 65: staging writes <=2-way)
    __shared__ float Vs[YKT][68];     // [m][c]
    const int mode = blockIdx.z;
    const int n0 = blockIdx.y * 64;
    const int c0 = blockIdx.x * 64;
    const int t  = threadIdx.x;
    const int ty = t >> 4;            // row group (4 rows)
    const int tx = t & 15;            // col group (4 cols)

    const int srow = t >> 3;          // staging: S row (i=0: 0..31, i=1: +32)
    const int sq   = t & 7;           // staging: m-quad within YKT

    float rm0 = 0.f, rl0 = 0.f, rm1 = 0.f, rl1 = 0.f;
    if (mode == 0) {
        rm0 = rowm[n0 + srow];      rl0 = rowli[n0 + srow];
        rm1 = rowm[n0 + 32 + srow]; rl1 = rowli[n0 + 32 + srow];
    }

    float acc[4][4];
#pragma unroll
    for (int i = 0; i < 4; i++)
#pragma unroll
        for (int j = 0; j < 4; j++) acc[i][j] = 0.0f;

    for (int m0 = 0; m0 < NPIX; m0 += YKT) {
        __syncthreads();
        // stage S tile 64 x YKT -> P (transposed, softmax applied)
#pragma unroll
        for (int i = 0; i < 2; i++) {
            int row = srow + i * 32;
            float4 s4 = *(const float4*)(S + (size_t)(n0 + row) * NPIX + m0 + sq * 4);
            float p0, p1, p2, p3;
            if (mode == 0) {
                float mm = i ? rm1 : rm0;
                float li = i ? rl1 : rl0;
                p0 = __expf(s4.x - mm) * li;
                p1 = __expf(s4.y - mm) * li;
                p2 = __expf(s4.z - mm) * li;
                p3 = __expf(s4.w - mm) * li;
            } else {
                float4 cm4 = *(const float4*)(colm + m0 + sq * 4);
                float4 cl4 = *(const float4*)(colli + m0 + sq * 4);
                p0 = __expf(s4.x - cm4.x) * cl4.x;
                p1 = __expf(s4.y - cm4.y) * cl4.y;
                p2 = __expf(s4.z - cm4.z) * cl4.z;
                p3 = __expf(s4.w - cm4.w) * cl4.w;
            }
            PT[sq * 4 + 0][row] = p0;
            PT[sq * 4 + 1][row] = p1;
            PT[sq * 4 + 2][row] = p2;
            PT[sq * 4 + 3][row] = p3;
        }
        // stage V tile YKT x 64
#pragma unroll
        for (int i = 0; i < 2; i++) {
            int L = t + i * 256;
            int mr = L >> 4, cq = L & 15;
            *(float4*)&Vs[mr][cq * 4] =
                *(const float4*)(V + (size_t)(m0 + mr) * CC + c0 + cq * 4);
        }
        __syncthreads();
#pragma unroll
        for (int kk = 0; kk < YKT; kk++) {
            float a[4], b[4];
            *(float4*)&a[0] = *(const float4*)&PT[kk][ty * 4];
            *(float4*)&b[0] = *(const float4*)&Vs[kk][tx * 4];
#pragma unroll
            for (int i = 0; i < 4; i++)
#pragma unroll
                for (int j = 0; j < 4; j++)
                    acc[i][j] = fmaf(a[i], b[j], acc[i][j]);
        }
    }

    float* Y = mode ? Y2 : Y1;
#pragma unroll
    for (int i = 0; i < 4; i++) {
        int row = n0 + ty * 4 + i;
        float4 o;
        o.x = acc[i][0]; o.y = acc[i][1]; o.z = acc[i][2]; o.w = acc[i][3];
        *(float4*)(Y + (size_t)row * CC + c0 + tx * 4) = o;
    }
}

// Final: out[b][ch][pix] = relu(x[b][ch&255][pix] + bias[ch] + sum_c W[ch][c]*Y[b][pix][c])
// NT GEMM 128x128 tiles; grid (pixtiles=32, chtiles=4, b=4)
__global__ __launch_bounds__(256) void out_kernel(
    const float* __restrict__ w_o1, const float* __restrict__ b_o1,
    const float* __restrict__ w_o2, const float* __restrict__ b_o2,
    const float* __restrict__ Y1, const float* __restrict__ Y2,
    const float* __restrict__ x, float* __restrict__ out)
{
    __shared__ float AsT[KT][132];    // [k][ch]
    __shared__ float BsT[KT][132];    // [k][pix]
    const int b    = blockIdx.z;
    const int ch0  = blockIdx.y * 128;          // 0..511
    const int pix0 = blockIdx.x * 128;
    const float* W    = (ch0 < 256) ? w_o1 : w_o2;
    const float* bias = (ch0 < 256) ? b_o1 : b_o2;
    const float* Y    = ((ch0 < 256) ? Y1 : Y2) + (size_t)b * NPIX * CC;
    const int chW0 = ch0 & 255;

    const int t  = threadIdx.x;
    const int ty = t >> 4;            // ch group (8 rows)
    const int tx = t & 15;            // pix group (4+4, split by 64)

    float acc[8][8];
#pragma unroll
    for (int i = 0; i < 8; i++)
#pragma unroll
        for (int j = 0; j < 8; j++) acc[i][j] = 0.0f;

    for (int k0 = 0; k0 < 256; k0 += KT) {
#pragma unroll
        for (int L = t; L < 512; L += 256) {
            int row = L >> 2, kq = L & 3;
            float4 v = *(const float4*)(W + (size_t)(chW0 + row) * 256 + k0 + kq * 4);
            AsT[kq * 4 + 0][row] = v.x;
            AsT[kq * 4 + 1][row] = v.y;
            AsT[kq * 4 + 2][row] = v.z;
            AsT[kq * 4 + 3][row] = v.w;
        }
#pragma unroll
        for (int L = t; L < 512; L += 256) {
            int row = L >> 2, kq = L & 3;
            float4 v = *(const float4*)(Y + (size_t)(pix0 + row) * 256 + k0 + kq * 4);
            BsT[kq * 4 + 0][row] = v.x;
            BsT[kq * 4 + 1][row] = v.y;
            BsT[kq * 4 + 2][row] = v.z;
            BsT[kq * 4 + 3][row] = v.w;
        }
        __syncthreads();
#pragma unroll
        for (int kk = 0; kk < KT; kk++) {
            float a[8], bb[8];
            *(float4*)&a[0]  = *(const float4*)&AsT[kk][ty * 8];
            *(float4*)&a[4]  = *(const float4*)&AsT[kk][ty * 8 + 4];
            *(float4*)&bb[0] = *(const float4*)&BsT[kk][tx * 4];
            *(float4*)&bb[4] = *(const float4*)&BsT[kk][64 + tx * 4];
#pragma unroll
            for (int i = 0; i < 8; i++)
#pragma unroll
                for (int j = 0; j < 8; j++)
                    acc[i][j] = fmaf(a[i], bb[j], acc[i][j]);
        }
        __syncthreads();
    }

#pragma unroll
    for (int i = 0; i < 8; i++) {
        int ch = ch0 + ty * 8 + i;
        float bval = bias[ch & 255];
        const float* xr = x + ((size_t)b * CC + (ch & 255)) * NPIX + pix0 + tx * 4;
        float4 xa = *(const float4*)xr;
        float4 xb = *(const float4*)(xr + 64);
        float4 r0, r1;
        r0.x = fmaxf(acc[i][0] + bval + xa.x, 0.0f);
        r0.y = fmaxf(acc[i][1] + bval + xa.y, 0.0f);
        r0.z = fmaxf(acc[i][2] + bval + xa.z, 0.0f);
        r0.w = fmaxf(acc[i][3] + bval + xa.w, 0.0f);
        r1.x = fmaxf(acc[i][4] + bval + xb.x, 0.0f);
        r1.y = fmaxf(acc[i][5] + bval + xb.y, 0.0f);
        r1.z = fmaxf(acc[i][6] + bval + xb.z, 0.0f);
        r1.w = fmaxf(acc[i][7] + bval + xb.w, 0.0f);
        float* orow = out + ((size_t)b * 2 * CC + ch) * NPIX + pix0 + tx * 4;
        *(float4*)orow = r0;
        *(float4*)(orow + 64) = r1;
    }
}

extern "C" void kernel_launch(void* const* d_in, const int* in_sizes, int n_in,
                              void* d_out, int out_size, void* d_ws, size_t ws_size,
                              hipStream_t stream)
{
    (void)in_sizes; (void)n_in; (void)out_size; (void)ws_size;
    const float* x      = (const float*)d_in[0];
    const float* w_teta = (const float*)d_in[1];
    const float* b_teta = (const float*)d_in[2];
    const float* w_fi   = (const float*)d_in[3];
    const float* b_fi   = (const float*)d_in[4];
    const float* w_gi   = (const float*)d_in[5];
    const float* b_gi   = (const float*)d_in[6];
    const float* w_o1   = (const float*)d_in[7];
    const float* b_o1   = (const float*)d_in[8];
    const float* w_o2   = (const float*)d_in[9];
    const float* b_o2   = (const float*)d_in[10];
    float* out = (float*)d_out;

    // workspace layout (floats): ~36.3M floats = ~145 MB
    float* ws = (float*)d_ws;
    const size_t CN = (size_t)CC * NPIX;       // 1M
    float* x1    = ws;                         // BB*CN
    float* x2    = x1 + BB * CN;
    float* x3    = x2 + BB * CN;
    float* Y1    = x3 + BB * CN;
    float* Y2    = Y1 + BB * CN;
    float* S     = Y2 + BB * CN;               // NPIX*NPIX
    float* rowm  = S + (size_t)NPIX * NPIX;
    float* rowli = rowm + NPIX;
    float* cm    = rowli + NPIX;
    float* cli   = cm + NPIX;
    float* pm    = cli + NPIX;                 // 32*NPIX
    float* pl    = pm + 32 * NPIX;

    dim3 blk(256);
    proj_kernel<<<dim3(32, 2, 12), blk, 0, stream>>>(
        x, w_teta, b_teta, w_fi, b_fi, w_gi, b_gi, x1, x2, x3);

    for (int b = 0; b < BB; b++) {
        scores_kernel<<<dim3(32, 32), blk, 0, stream>>>(x1 + b * CN, x2 + b * CN, S);
        rowstats_kernel<<<dim3(NPIX), blk, 0, stream>>>(S, rowm, rowli);
        colstats1_kernel<<<dim3(16, 32), blk, 0, stream>>>(S, pm, pl);
        colstats2_kernel<<<dim3(16), blk, 0, stream>>>(pm, pl, cm, cli);
        ysoft_kernel<<<dim3(4, 64, 2), blk, 0, stream>>>(
            S, x3 + b * CN, rowm, rowli, cm, cli, Y1 + b * CN, Y2 + b * CN);
    }

    out_kernel<<<dim3(32, 4, 4), blk, 0, stream>>>(
        w_o1, b_o1, w_o2, b_o2, Y1, Y2, x, out);
}

// Round 3
// 1230.938 us; speedup vs baseline: 2.4589x; 1.6390x over previous
//
#include <hip/hip_runtime.h>

#define BB   4
#define CC   256
#define NPIX 4096
#define KT   16
#define AST  40   // LDS row stride (bf16 units): 80 B, 16B-aligned, conflict-free b128 phases

typedef __attribute__((ext_vector_type(8)))  short bf16x8;
typedef __attribute__((ext_vector_type(4)))  short short4v;
typedef __attribute__((ext_vector_type(16))) float f32x16;

__device__ __forceinline__ short f2bf(float f) {
    unsigned u = __float_as_uint(f);
    u = u + 0x7fff + ((u >> 16) & 1);   // RNE
    return (short)(u >> 16);
}

// ---------------------------------------------------------------------------
// 128x128-tile fp32 NN GEMM body, K=256 fixed, lda=256, ldb=ldOut=4096.
// ---------------------------------------------------------------------------
__device__ __forceinline__ void gemm128_nn_k256(
    const float* __restrict__ A, const float* __restrict__ Bm,
    const float* __restrict__ bias, float* __restrict__ Out,
    int tm0, int tn0)
{
    __shared__ float AsT[KT][132];   // [k][m], padded
    __shared__ float Bs[KT][132];    // [k][n], padded
    const int t  = threadIdx.x;
    const int ty = t >> 4;           // row group (8 rows each)
    const int tx = t & 15;           // col group (4+4 cols, split by 64)

    float acc[8][8];
#pragma unroll
    for (int i = 0; i < 8; i++)
#pragma unroll
        for (int j = 0; j < 8; j++) acc[i][j] = 0.0f;

    for (int k0 = 0; k0 < 256; k0 += KT) {
#pragma unroll
        for (int L = t; L < 512; L += 256) {
            int row = L >> 2, kq = L & 3;
            float4 v = *(const float4*)(A + (size_t)(tm0 + row) * 256 + k0 + kq * 4);
            AsT[kq * 4 + 0][row] = v.x;
            AsT[kq * 4 + 1][row] = v.y;
            AsT[kq * 4 + 2][row] = v.z;
            AsT[kq * 4 + 3][row] = v.w;
        }
#pragma unroll
        for (int L = t; L < 512; L += 256) {
            int kr = L >> 5, nq = L & 31;
            float4 v = *(const float4*)(Bm + (size_t)(k0 + kr) * NPIX + tn0 + nq * 4);
            *(float4*)&Bs[kr][nq * 4] = v;
        }
        __syncthreads();
#pragma unroll
        for (int kk = 0; kk < KT; kk++) {
            float a[8], b[8];
            *(float4*)&a[0] = *(const float4*)&AsT[kk][ty * 8];
            *(float4*)&a[4] = *(const float4*)&AsT[kk][ty * 8 + 4];
            *(float4*)&b[0] = *(const float4*)&Bs[kk][tx * 4];
            *(float4*)&b[4] = *(const float4*)&Bs[kk][64 + tx * 4];
#pragma unroll
            for (int i = 0; i < 8; i++)
#pragma unroll
                for (int j = 0; j < 8; j++)
                    acc[i][j] = fmaf(a[i], b[j], acc[i][j]);
        }
        __syncthreads();
    }

#pragma unroll
    for (int i = 0; i < 8; i++) {
        int row = tm0 + ty * 8 + i;
        float bval = bias ? bias[row] : 0.0f;
        float4 o0, o1;
        o0.x = acc[i][0] + bval; o0.y = acc[i][1] + bval;
        o0.z = acc[i][2] + bval; o0.w = acc[i][3] + bval;
        o1.x = acc[i][4] + bval; o1.y = acc[i][5] + bval;
        o1.z = acc[i][6] + bval; o1.w = acc[i][7] + bval;
        float* orow = Out + (size_t)row * NPIX + tn0 + tx * 4;
        *(float4*)orow = o0;
        *(float4*)(orow + 64) = o1;
    }
}

__global__ __launch_bounds__(256) void proj_kernel(
    const float* __restrict__ x,
    const float* __restrict__ w0, const float* __restrict__ bi0,
    const float* __restrict__ w1, const float* __restrict__ bi1,
    const float* __restrict__ w2, const float* __restrict__ bi2,
    float* __restrict__ o0, float* __restrict__ o1, float* __restrict__ o2)
{
    int z = blockIdx.z;
    int p = z >> 2, b = z & 3;
    const float* W    = (p == 0) ? w0  : (p == 1) ? w1  : w2;
    const float* bias = (p == 0) ? bi0 : (p == 1) ? bi1 : bi2;
    float*       O    = (p == 0) ? o0  : (p == 1) ? o1  : o2;
    size_t off = (size_t)b * CC * NPIX;
    gemm128_nn_k256(W, x + off, bias, O + off, blockIdx.y * 128, blockIdx.x * 128);
}

__global__ __launch_bounds__(256) void scores_kernel(
    const float* __restrict__ x1b, const float* __restrict__ x2b, float* __restrict__ S)
{
    gemm128_nn_k256(x1b, x2b, nullptr, S, blockIdx.y * 128, blockIdx.x * 128);
}

__global__ __launch_bounds__(256) void rowstats_kernel(
    const float* __restrict__ S, float* __restrict__ rowm, float* __restrict__ rowli)
{
    int n = blockIdx.x;
    const float* r = S + (size_t)n * NPIX;
    int t = threadIdx.x;
    float m = -1e30f, l = 0.0f;
    for (int i = t; i < NPIX; i += 256) {
        float v = r[i];
        float mn = fmaxf(m, v);
        l = l * __expf(m - mn) + __expf(v - mn);
        m = mn;
    }
    for (int off = 32; off; off >>= 1) {
        float m2 = __shfl_xor(m, off, 64);
        float l2 = __shfl_xor(l, off, 64);
        float mn = fmaxf(m, m2);
        l = l * __expf(m - mn) + l2 * __expf(m2 - mn);
        m = mn;
    }
    __shared__ float sm[4], sl[4];
    int w = t >> 6;
    if ((t & 63) == 0) { sm[w] = m; sl[w] = l; }
    __syncthreads();
    if (t == 0) {
        m = sm[0]; l = sl[0];
        for (int i = 1; i < 4; i++) {
            float mn = fmaxf(m, sm[i]);
            l = l * __expf(m - mn) + sl[i] * __expf(sm[i] - mn);
            m = mn;
        }
        rowm[n]  = m;
        rowli[n] = 1.0f / l;
    }
}

__global__ __launch_bounds__(256) void colstats1_kernel(
    const float* __restrict__ S, float* __restrict__ pm, float* __restrict__ pl)
{
    int col = blockIdx.x * 256 + threadIdx.x;
    int r0  = blockIdx.y * 128;
    float m = -1e30f, l = 0.0f;
    for (int r = 0; r < 128; r++) {
        float v = S[(size_t)(r0 + r) * NPIX + col];
        float mn = fmaxf(m, v);
        l = l * __expf(m - mn) + __expf(v - mn);
        m = mn;
    }
    pm[(size_t)blockIdx.y * NPIX + col] = m;
    pl[(size_t)blockIdx.y * NPIX + col] = l;
}

__global__ __launch_bounds__(256) void colstats2_kernel(
    const float* __restrict__ pm, const float* __restrict__ pl,
    float* __restrict__ cm, float* __restrict__ cli)
{
    int col = blockIdx.x * 256 + threadIdx.x;
    float m = -1e30f, l = 0.0f;
    for (int i = 0; i < 32; i++) {
        float m2 = pm[(size_t)i * NPIX + col];
        float l2 = pl[(size_t)i * NPIX + col];
        float mn = fmaxf(m, m2);
        l = l * __expf(m - mn) + l2 * __expf(m2 - mn);
        m = mn;
    }
    cm[col]  = m;
    cli[col] = 1.0f / l;
}

// Vt[c][m] = bf16(x3view[m][c]) = bf16(x3.flat[m*256+c]); tiled LDS transpose.
// grid (m-tiles=128, c-tiles=8, batch=4), 256 threads.
__global__ __launch_bounds__(256) void packVt_kernel(
    const float* __restrict__ x3, short* __restrict__ Vt)
{
    __shared__ short T[32][33];
    const int b  = blockIdx.z;
    const int m0 = blockIdx.x * 32;
    const int c0 = blockIdx.y * 32;
    const float* in = x3 + (size_t)b * CC * NPIX;
    short* out = Vt + (size_t)b * CC * NPIX;
    const int t = threadIdx.x;
    const int r = t >> 3, q = t & 7;
    float4 v = *(const float4*)(in + (size_t)(m0 + r) * CC + c0 + q * 4);
    T[q * 4 + 0][r] = f2bf(v.x);
    T[q * 4 + 1][r] = f2bf(v.y);
    T[q * 4 + 2][r] = f2bf(v.z);
    T[q * 4 + 3][r] = f2bf(v.w);
    __syncthreads();
    short4v o;
    o.x = T[r][q * 4 + 0];
    o.y = T[r][q * 4 + 1];
    o.z = T[r][q * 4 + 2];
    o.w = T[r][q * 4 + 3];
    *(short4v*)(out + (size_t)(c0 + r) * NPIX + m0 + q * 4) = o;
}

// Y = softmax(S) @ V via bf16 MFMA.
// block tile 64n x 64c, 4 waves each one 32x32 mfma tile; K(m)-step 32.
// grid (c-tiles=4, n-tiles=64, mode=2) = 512 blocks.
__global__ __launch_bounds__(256) void ysoft_mfma(
    const float* __restrict__ S, const short* __restrict__ Vt,
    const float* __restrict__ rowm, const float* __restrict__ rowli,
    const float* __restrict__ colm, const float* __restrict__ colli,
    float* __restrict__ Y1, float* __restrict__ Y2)
{
    __shared__ short Pa[64 * AST];   // P tile [n 64][m 32], bf16
    __shared__ short Vb[64 * AST];   // V tile [c 64][m 32], bf16
    const int mode = blockIdx.z;
    const int c0 = blockIdx.x * 64;
    const int n0 = blockIdx.y * 64;
    const int t = threadIdx.x;
    const int lane = t & 63;
    const int w = t >> 6;
    const int l31 = lane & 31;
    const int l5  = lane >> 5;
    const int nstripe = (w & 1) * 32;
    const int cstripe = (w >> 1) * 32;

    const int pr = t >> 2;   // staging row 0..63
    const int pq = t & 3;    // staging m-octet 0..3

    float sm_n = 0.f, sl_n = 0.f;
    if (mode == 0) { sm_n = rowm[n0 + pr]; sl_n = rowli[n0 + pr]; }

    f32x16 acc = {};

    for (int m0 = 0; m0 < NPIX; m0 += 32) {
        __syncthreads();
        // stage P: S[n0+pr][m0+pq*8 .. +8], softmax-exp, -> bf16
        const float* sp = S + (size_t)(n0 + pr) * NPIX + m0 + pq * 8;
        float4 a0 = *(const float4*)sp;
        float4 a1 = *(const float4*)(sp + 4);
        bf16x8 ov;
        if (mode == 0) {
            ov[0] = f2bf(__expf(a0.x - sm_n) * sl_n);
            ov[1] = f2bf(__expf(a0.y - sm_n) * sl_n);
            ov[2] = f2bf(__expf(a0.z - sm_n) * sl_n);
            ov[3] = f2bf(__expf(a0.w - sm_n) * sl_n);
            ov[4] = f2bf(__expf(a1.x - sm_n) * sl_n);
            ov[5] = f2bf(__expf(a1.y - sm_n) * sl_n);
            ov[6] = f2bf(__expf(a1.z - sm_n) * sl_n);
            ov[7] = f2bf(__expf(a1.w - sm_n) * sl_n);
        } else {
            const float* cmp = colm + m0 + pq * 8;
            const float* clp = colli + m0 + pq * 8;
            float4 cm0 = *(const float4*)cmp, cm1 = *(const float4*)(cmp + 4);
            float4 cl0 = *(const float4*)clp, cl1 = *(const float4*)(clp + 4);
            ov[0] = f2bf(__expf(a0.x - cm0.x) * cl0.x);
            ov[1] = f2bf(__expf(a0.y - cm0.y) * cl0.y);
            ov[2] = f2bf(__expf(a0.z - cm0.z) * cl0.z);
            ov[3] = f2bf(__expf(a0.w - cm0.w) * cl0.w);
            ov[4] = f2bf(__expf(a1.x - cm1.x) * cl1.x);
            ov[5] = f2bf(__expf(a1.y - cm1.y) * cl1.y);
            ov[6] = f2bf(__expf(a1.z - cm1.z) * cl1.z);
            ov[7] = f2bf(__expf(a1.w - cm1.w) * cl1.w);
        }
        *(bf16x8*)&Pa[pr * AST + pq * 8] = ov;
        // stage V: Vt[c0+pr][m0+pq*8 .. +8]
        *(bf16x8*)&Vb[pr * AST + pq * 8] =
            *(const bf16x8*)(Vt + (size_t)(c0 + pr) * NPIX + m0 + pq * 8);
        __syncthreads();

        // A-frag: lane m=l31 (row of Y tile), k=l5*8+j ; B-frag: lane n=l31 (c), same k
        const short* pA = &Pa[(nstripe + l31) * AST + l5 * 8];
        const short* pB = &Vb[(cstripe + l31) * AST + l5 * 8];
        bf16x8 af0 = *(const bf16x8*)pA;
        bf16x8 af1 = *(const bf16x8*)(pA + 16);
        bf16x8 bf0 = *(const bf16x8*)pB;
        bf16x8 bf1 = *(const bf16x8*)(pB + 16);
        acc = __builtin_amdgcn_mfma_f32_32x32x16_bf16(af0, bf0, acc, 0, 0, 0);
        acc = __builtin_amdgcn_mfma_f32_32x32x16_bf16(af1, bf1, acc, 0, 0, 0);
    }

    float* Y = mode ? Y2 : Y1;
#pragma unroll
    for (int r = 0; r < 16; r++) {
        int row = (r & 3) + 8 * (r >> 2) + 4 * l5;   // verified m74/m101 C/D layout
        Y[(size_t)(n0 + nstripe + row) * CC + c0 + cstripe + l31] = acc[r];
    }
}

// Final fused epilogue GEMM (fp32, unchanged)
__global__ __launch_bounds__(256) void out_kernel(
    const float* __restrict__ w_o1, const float* __restrict__ b_o1,
    const float* __restrict__ w_o2, const float* __restrict__ b_o2,
    const float* __restrict__ Y1, const float* __restrict__ Y2,
    const float* __restrict__ x, float* __restrict__ out)
{
    __shared__ float AsT[KT][132];
    __shared__ float BsT[KT][132];
    const int b    = blockIdx.z;
    const int ch0  = blockIdx.y * 128;
    const int pix0 = blockIdx.x * 128;
    const float* W    = (ch0 < 256) ? w_o1 : w_o2;
    const float* bias = (ch0 < 256) ? b_o1 : b_o2;
    const float* Y    = ((ch0 < 256) ? Y1 : Y2) + (size_t)b * NPIX * CC;
    const int chW0 = ch0 & 255;

    const int t  = threadIdx.x;
    const int ty = t >> 4;
    const int tx = t & 15;

    float acc[8][8];
#pragma unroll
    for (int i = 0; i < 8; i++)
#pragma unroll
        for (int j = 0; j < 8; j++) acc[i][j] = 0.0f;

    for (int k0 = 0; k0 < 256; k0 += KT) {
#pragma unroll
        for (int L = t; L < 512; L += 256) {
            int row = L >> 2, kq = L & 3;
            float4 v = *(const float4*)(W + (size_t)(chW0 + row) * 256 + k0 + kq * 4);
            AsT[kq * 4 + 0][row] = v.x;
            AsT[kq * 4 + 1][row] = v.y;
            AsT[kq * 4 + 2][row] = v.z;
            AsT[kq * 4 + 3][row] = v.w;
        }
#pragma unroll
        for (int L = t; L < 512; L += 256) {
            int row = L >> 2, kq = L & 3;
            float4 v = *(const float4*)(Y + (size_t)(pix0 + row) * 256 + k0 + kq * 4);
            BsT[kq * 4 + 0][row] = v.x;
            BsT[kq * 4 + 1][row] = v.y;
            BsT[kq * 4 + 2][row] = v.z;
            BsT[kq * 4 + 3][row] = v.w;
        }
        __syncthreads();
#pragma unroll
        for (int kk = 0; kk < KT; kk++) {
            float a[8], bb[8];
            *(float4*)&a[0]  = *(const float4*)&AsT[kk][ty * 8];
            *(float4*)&a[4]  = *(const float4*)&AsT[kk][ty * 8 + 4];
            *(float4*)&bb[0] = *(const float4*)&BsT[kk][tx * 4];
            *(float4*)&bb[4] = *(const float4*)&BsT[kk][64 + tx * 4];
#pragma unroll
            for (int i = 0; i < 8; i++)
#pragma unroll
                for (int j = 0; j < 8; j++)
                    acc[i][j] = fmaf(a[i], bb[j], acc[i][j]);
        }
        __syncthreads();
    }

#pragma unroll
    for (int i = 0; i < 8; i++) {
        int ch = ch0 + ty * 8 + i;
        float bval = bias[ch & 255];
        const float* xr = x + ((size_t)b * CC + (ch & 255)) * NPIX + pix0 + tx * 4;
        float4 xa = *(const float4*)xr;
        float4 xb = *(const float4*)(xr + 64);
        float4 r0, r1;
        r0.x = fmaxf(acc[i][0] + bval + xa.x, 0.0f);
        r0.y = fmaxf(acc[i][1] + bval + xa.y, 0.0f);
        r0.z = fmaxf(acc[i][2] + bval + xa.z, 0.0f);
        r0.w = fmaxf(acc[i][3] + bval + xa.w, 0.0f);
        r1.x = fmaxf(acc[i][4] + bval + xb.x, 0.0f);
        r1.y = fmaxf(acc[i][5] + bval + xb.y, 0.0f);
        r1.z = fmaxf(acc[i][6] + bval + xb.z, 0.0f);
        r1.w = fmaxf(acc[i][7] + bval + xb.w, 0.0f);
        float* orow = out + ((size_t)b * 2 * CC + ch) * NPIX + pix0 + tx * 4;
        *(float4*)orow = r0;
        *(float4*)(orow + 64) = r1;
    }
}

extern "C" void kernel_launch(void* const* d_in, const int* in_sizes, int n_in,
                              void* d_out, int out_size, void* d_ws, size_t ws_size,
                              hipStream_t stream)
{
    (void)in_sizes; (void)n_in; (void)out_size; (void)ws_size;
    const float* x      = (const float*)d_in[0];
    const float* w_teta = (const float*)d_in[1];
    const float* b_teta = (const float*)d_in[2];
    const float* w_fi   = (const float*)d_in[3];
    const float* b_fi   = (const float*)d_in[4];
    const float* w_gi   = (const float*)d_in[5];
    const float* b_gi   = (const float*)d_in[6];
    const float* w_o1   = (const float*)d_in[7];
    const float* b_o1   = (const float*)d_in[8];
    const float* w_o2   = (const float*)d_in[9];
    const float* b_o2   = (const float*)d_in[10];
    float* out = (float*)d_out;

    float* ws = (float*)d_ws;
    const size_t CN = (size_t)CC * NPIX;       // 1M
    float* x1    = ws;                         // BB*CN
    float* x2    = x1 + BB * CN;
    float* x3    = x2 + BB * CN;
    float* Y1    = x3 + BB * CN;
    float* Y2    = Y1 + BB * CN;
    float* S     = Y2 + BB * CN;               // NPIX*NPIX
    float* rowm  = S + (size_t)NPIX * NPIX;
    float* rowli = rowm + NPIX;
    float* cm    = rowli + NPIX;
    float* cli   = cm + NPIX;
    float* pm    = cli + NPIX;                 // 32*NPIX
    float* pl    = pm + 32 * NPIX;
    short* Vtb   = (short*)(pl + 32 * NPIX);   // BB*CN bf16

    dim3 blk(256);
    proj_kernel<<<dim3(32, 2, 12), blk, 0, stream>>>(
        x, w_teta, b_teta, w_fi, b_fi, w_gi, b_gi, x1, x2, x3);

    packVt_kernel<<<dim3(128, 8, 4), blk, 0, stream>>>(x3, Vtb);

    for (int b = 0; b < BB; b++) {
        scores_kernel<<<dim3(32, 32), blk, 0, stream>>>(x1 + b * CN, x2 + b * CN, S);
        rowstats_kernel<<<dim3(NPIX), blk, 0, stream>>>(S, rowm, rowli);
        colstats1_kernel<<<dim3(16, 32), blk, 0, stream>>>(S, pm, pl);
        colstats2_kernel<<<dim3(16), blk, 0, stream>>>(pm, pl, cm, cli);
        ysoft_mfma<<<dim3(4, 64, 2), blk, 0, stream>>>(
            S, Vtb + b * CN, rowm, rowli, cm, cli, Y1 + b * CN, Y2 + b * CN);
    }

    out_kernel<<<dim3(32, 4, 4), blk, 0, stream>>>(
        w_o1, b_o1, w_o2, b_o2, Y1, Y2, x, out);
}

// Round 5
// 842.201 us; speedup vs baseline: 3.5939x; 1.4616x over previous
//
#include <hip/hip_runtime.h>

#define BB   4
#define CC   256
#define NPIX 4096
#define AST  40    // ysoft LDS row stride (shorts)
#define AST2 40    // mfma-core LDS row stride (shorts), 80 B, 16B-aligned

typedef __attribute__((ext_vector_type(8)))  short bf16x8;
typedef __attribute__((ext_vector_type(4)))  short short4v;
typedef __attribute__((ext_vector_type(16))) float f32x16;

__device__ __forceinline__ short f2bf(float f) {
    unsigned u = __float_as_uint(f);
    u = u + 0x7fff + ((u >> 16) & 1);   // RNE
    return (short)(u >> 16);
}
__device__ __forceinline__ float bf2f(short s) {
    return __uint_as_float(((unsigned)(unsigned short)s) << 16);
}
__device__ __forceinline__ void split_bf(float v, short& hi, short& lo) {
    hi = f2bf(v);
    lo = f2bf(v - bf2f(hi));
}
__device__ __forceinline__ int cdrow(int r, int l5) {
    return (r & 3) + 8 * (r >> 2) + 4 * l5;   // verified m74/m101 C/D row map
}

// ---------------------------------------------------------------------------
// hi/lo split-bf16 MFMA core: 128x128 tile, K=256, A/B row-major [row][256].
// 4 waves, each owns 64x64 quadrant (2x2 of 32x32). 3 MFMAs per product
// (hh + hl + lh) -> fp32-class accuracy at bf16-MFMA rate.
// ---------------------------------------------------------------------------
__device__ __forceinline__ void mfma_core_hilo(
    const short* __restrict__ Ahi, const short* __restrict__ Alo,
    const short* __restrict__ Bhi, const short* __restrict__ Blo,
    f32x16 acc[2][2])
{
    __shared__ short LAh[128 * AST2], LAl[128 * AST2];
    __shared__ short LBh[128 * AST2], LBl[128 * AST2];
    const int t = threadIdx.x;
    const int lane = t & 63, w = t >> 6;
    const int l31 = lane & 31, l5 = lane >> 5;
    const int nq = (w & 1) * 64, mq = (w >> 1) * 64;
    const int sr = t >> 1;              // staging row 0..127
    const int sk = (t & 1) * 16;        // staging k offset (shorts)
    const size_t gs = (size_t)sr * 256 + sk;
    const int ls = sr * AST2 + sk;

    for (int k0 = 0; k0 < 256; k0 += 32) {
        __syncthreads();
        *(bf16x8*)&LAh[ls]     = *(const bf16x8*)(Ahi + gs + k0);
        *(bf16x8*)&LAh[ls + 8] = *(const bf16x8*)(Ahi + gs + k0 + 8);
        *(bf16x8*)&LAl[ls]     = *(const bf16x8*)(Alo + gs + k0);
        *(bf16x8*)&LAl[ls + 8] = *(const bf16x8*)(Alo + gs + k0 + 8);
        *(bf16x8*)&LBh[ls]     = *(const bf16x8*)(Bhi + gs + k0);
        *(bf16x8*)&LBh[ls + 8] = *(const bf16x8*)(Bhi + gs + k0 + 8);
        *(bf16x8*)&LBl[ls]     = *(const bf16x8*)(Blo + gs + k0);
        *(bf16x8*)&LBl[ls + 8] = *(const bf16x8*)(Blo + gs + k0 + 8);
        __syncthreads();
#pragma unroll
        for (int ks = 0; ks < 2; ks++) {
            bf16x8 ah[2], al[2], bh[2], bl[2];
#pragma unroll
            for (int s = 0; s < 2; s++) {
                int ra = (nq + s * 32 + l31) * AST2 + ks * 16 + l5 * 8;
                int rb = (mq + s * 32 + l31) * AST2 + ks * 16 + l5 * 8;
                ah[s] = *(const bf16x8*)&LAh[ra];
                al[s] = *(const bf16x8*)&LAl[ra];
                bh[s] = *(const bf16x8*)&LBh[rb];
                bl[s] = *(const bf16x8*)&LBl[rb];
            }
#pragma unroll
            for (int s = 0; s < 2; s++)
#pragma unroll
                for (int u = 0; u < 2; u++) {
                    acc[s][u] = __builtin_amdgcn_mfma_f32_32x32x16_bf16(ah[s], bh[u], acc[s][u], 0, 0, 0);
                    acc[s][u] = __builtin_amdgcn_mfma_f32_32x32x16_bf16(ah[s], bl[u], acc[s][u], 0, 0, 0);
                    acc[s][u] = __builtin_amdgcn_mfma_f32_32x32x16_bf16(al[s], bh[u], acc[s][u], 0, 0, 0);
                }
        }
    }
}

// Single-bf16 variant (for the output GEMM).
__device__ __forceinline__ void mfma_core_single(
    const short* __restrict__ A, const short* __restrict__ B, f32x16 acc[2][2])
{
    __shared__ short LA[128 * AST2], LB[128 * AST2];
    const int t = threadIdx.x;
    const int lane = t & 63, w = t >> 6;
    const int l31 = lane & 31, l5 = lane >> 5;
    const int nq = (w & 1) * 64, mq = (w >> 1) * 64;
    const int sr = t >> 1;
    const int sk = (t & 1) * 16;
    const size_t gs = (size_t)sr * 256 + sk;
    const int ls = sr * AST2 + sk;

    for (int k0 = 0; k0 < 256; k0 += 32) {
        __syncthreads();
        *(bf16x8*)&LA[ls]     = *(const bf16x8*)(A + gs + k0);
        *(bf16x8*)&LA[ls + 8] = *(const bf16x8*)(A + gs + k0 + 8);
        *(bf16x8*)&LB[ls]     = *(const bf16x8*)(B + gs + k0);
        *(bf16x8*)&LB[ls + 8] = *(const bf16x8*)(B + gs + k0 + 8);
        __syncthreads();
#pragma unroll
        for (int ks = 0; ks < 2; ks++) {
            bf16x8 a[2], b[2];
#pragma unroll
            for (int s = 0; s < 2; s++) {
                a[s] = *(const bf16x8*)&LA[(nq + s * 32 + l31) * AST2 + ks * 16 + l5 * 8];
                b[s] = *(const bf16x8*)&LB[(mq + s * 32 + l31) * AST2 + ks * 16 + l5 * 8];
            }
#pragma unroll
            for (int s = 0; s < 2; s++)
#pragma unroll
                for (int u = 0; u < 2; u++)
                    acc[s][u] = __builtin_amdgcn_mfma_f32_32x32x16_bf16(a[s], b[u], acc[s][u], 0, 0, 0);
        }
    }
}

// ---------------- pack kernels ----------------

// proj weights -> hi/lo bf16 (elementwise). grid (64, 3)
__global__ __launch_bounds__(256) void pack_w_hilo(
    const float* __restrict__ w0, const float* __restrict__ w1, const float* __restrict__ w2,
    short* __restrict__ whi, short* __restrict__ wlo)
{
    int which = blockIdx.y;
    const float* w = which == 0 ? w0 : which == 1 ? w1 : w2;
    int idx = blockIdx.x * 1024 + threadIdx.x * 4;
    float4 v = *(const float4*)(w + idx);
    short4v h, l;
    short th, tl;
    split_bf(v.x, th, tl); h.x = th; l.x = tl;
    split_bf(v.y, th, tl); h.y = th; l.y = tl;
    split_bf(v.z, th, tl); h.z = th; l.z = tl;
    split_bf(v.w, th, tl); h.w = th; l.w = tl;
    *(short4v*)(whi + which * 65536 + idx) = h;
    *(short4v*)(wlo + which * 65536 + idx) = l;
}

// out weights -> single bf16. grid (64, 2)
__global__ __launch_bounds__(256) void pack_w_out(
    const float* __restrict__ w1, const float* __restrict__ w2, short* __restrict__ wob)
{
    int which = blockIdx.y;
    const float* w = which == 0 ? w1 : w2;
    int idx = blockIdx.x * 1024 + threadIdx.x * 4;
    float4 v = *(const float4*)(w + idx);
    short4v h;
    h.x = f2bf(v.x); h.y = f2bf(v.y); h.z = f2bf(v.z); h.w = f2bf(v.w);
    *(short4v*)(wob + which * 65536 + idx) = h;
}

// transpose + split: in [b][256][4096] fp32 -> out [b][4096][256] hi/lo bf16.
// grid (128, 8, 4)
__global__ __launch_bounds__(256) void pack_t_split(
    const float* __restrict__ in, short* __restrict__ ohi, short* __restrict__ olo)
{
    __shared__ short Th[32][36], Tl[32][36];
    const int b  = blockIdx.z;
    const int n0 = blockIdx.x * 32;
    const int c0 = blockIdx.y * 32;
    const float* src = in + (size_t)b * CC * NPIX;
    const int t = threadIdx.x;
    const int r = t >> 3, q = t & 7;
    float4 v = *(const float4*)(src + (size_t)(c0 + r) * NPIX + n0 + q * 4);
    short h, l;
    split_bf(v.x, h, l); Th[q * 4 + 0][r] = h; Tl[q * 4 + 0][r] = l;
    split_bf(v.y, h, l); Th[q * 4 + 1][r] = h; Tl[q * 4 + 1][r] = l;
    split_bf(v.z, h, l); Th[q * 4 + 2][r] = h; Tl[q * 4 + 2][r] = l;
    split_bf(v.w, h, l); Th[q * 4 + 3][r] = h; Tl[q * 4 + 3][r] = l;
    __syncthreads();
    short4v oh, ol;
    oh.x = Th[r][q * 4 + 0]; ol.x = Tl[r][q * 4 + 0];
    oh.y = Th[r][q * 4 + 1]; ol.y = Tl[r][q * 4 + 1];
    oh.z = Th[r][q * 4 + 2]; ol.z = Tl[r][q * 4 + 2];
    oh.w = Th[r][q * 4 + 3]; ol.w = Tl[r][q * 4 + 3];
    size_t o = (size_t)b * CC * NPIX + (size_t)(n0 + r) * 256 + c0 + q * 4;
    *(short4v*)(ohi + o) = oh;
    *(short4v*)(olo + o) = ol;
}

// Vt[c][m] = bf16(x3.flat[m*256+c]); single bf16. grid (128, 8, 4)
__global__ __launch_bounds__(256) void packVt_kernel(
    const float* __restrict__ x3, short* __restrict__ Vt)
{
    __shared__ short T[32][33];
    const int b  = blockIdx.z;
    const int m0 = blockIdx.x * 32;
    const int c0 = blockIdx.y * 32;
    const float* in = x3 + (size_t)b * CC * NPIX;
    short* out = Vt + (size_t)b * CC * NPIX;
    const int t = threadIdx.x;
    const int r = t >> 3, q = t & 7;
    float4 v = *(const float4*)(in + (size_t)(m0 + r) * CC + c0 + q * 4);
    T[q * 4 + 0][r] = f2bf(v.x);
    T[q * 4 + 1][r] = f2bf(v.y);
    T[q * 4 + 2][r] = f2bf(v.z);
    T[q * 4 + 3][r] = f2bf(v.w);
    __syncthreads();
    short4v o;
    o.x = T[r][q * 4 + 0];
    o.y = T[r][q * 4 + 1];
    o.z = T[r][q * 4 + 2];
    o.w = T[r][q * 4 + 3];
    *(short4v*)(out + (size_t)(c0 + r) * NPIX + m0 + q * 4) = o;
}

// ---------------- GEMM kernels ----------------

// proj: out tile [c 128][n 128]; A=W hi/lo, B=xt hi/lo. grid (32, 2, 12)
__global__ __launch_bounds__(256) void proj_mfma(
    const short* __restrict__ wphi, const short* __restrict__ wplo,
    const short* __restrict__ xthi, const short* __restrict__ xtlo,
    const float* __restrict__ b_teta, const float* __restrict__ b_fi,
    const float* __restrict__ b_gi,
    short* __restrict__ x1hi, short* __restrict__ x1lo,
    float* __restrict__ x2, float* __restrict__ x3)
{
    const int z = blockIdx.z, p = z >> 2, b = z & 3;
    const int n0 = blockIdx.x * 128, c0 = blockIdx.y * 128;
    const size_t CN = (size_t)CC * NPIX;
    const short* Ah = wphi + p * 65536 + c0 * 256;
    const short* Al = wplo + p * 65536 + c0 * 256;
    const short* Bh = xthi + (size_t)b * CN + (size_t)n0 * 256;
    const short* Bl = xtlo + (size_t)b * CN + (size_t)n0 * 256;
    const float* bias = p == 0 ? b_teta : p == 1 ? b_fi : b_gi;

    f32x16 acc[2][2] = {};
    mfma_core_hilo(Ah, Al, Bh, Bl, acc);

    const int t = threadIdx.x, lane = t & 63, w = t >> 6;
    const int l31 = lane & 31, l5 = lane >> 5;
    const int aq = (w & 1) * 64, bq = (w >> 1) * 64;
#pragma unroll
    for (int s = 0; s < 2; s++)
#pragma unroll
        for (int u = 0; u < 2; u++)
#pragma unroll
            for (int r = 0; r < 16; r++) {
                int c = c0 + aq + s * 32 + cdrow(r, l5);
                int n = n0 + bq + u * 32 + l31;
                float v = acc[s][u][r] + bias[c];
                size_t o = (size_t)b * CN + (size_t)c * NPIX + n;
                if (p == 0) {
                    short h, l; split_bf(v, h, l);
                    x1hi[o] = h; x1lo[o] = l;
                } else if (p == 1) {
                    x2[o] = v;
                } else {
                    x3[o] = v;
                }
            }
}

// scores: S[n][m] = x1view[n][:] . x2t[m][:], hi/lo. grid (32, 32) per batch
__global__ __launch_bounds__(256) void scores_mfma(
    const short* __restrict__ x1hi, const short* __restrict__ x1lo,
    const short* __restrict__ x2thi, const short* __restrict__ x2tlo,
    float* __restrict__ S)
{
    const int m0 = blockIdx.x * 128, n0 = blockIdx.y * 128;
    f32x16 acc[2][2] = {};
    mfma_core_hilo(x1hi + (size_t)n0 * 256, x1lo + (size_t)n0 * 256,
                   x2thi + (size_t)m0 * 256, x2tlo + (size_t)m0 * 256, acc);

    const int t = threadIdx.x, lane = t & 63, w = t >> 6;
    const int l31 = lane & 31, l5 = lane >> 5;
    const int aq = (w & 1) * 64, bq = (w >> 1) * 64;
#pragma unroll
    for (int s = 0; s < 2; s++)
#pragma unroll
        for (int u = 0; u < 2; u++)
#pragma unroll
            for (int r = 0; r < 16; r++) {
                int n = n0 + aq + s * 32 + cdrow(r, l5);
                int m = m0 + bq + u * 32 + l31;
                S[(size_t)n * NPIX + m] = acc[s][u][r];
            }
}

// out: relu(x + bias + W.Y^T), single bf16. grid (32, 4, 4)
__global__ __launch_bounds__(256) void out_mfma(
    const short* __restrict__ wob,
    const float* __restrict__ b_o1, const float* __restrict__ b_o2,
    const short* __restrict__ Y1b, const short* __restrict__ Y2b,
    const float* __restrict__ x, float* __restrict__ out)
{
    const int b = blockIdx.z;
    const int ch0 = blockIdx.y * 128;
    const int pix0 = blockIdx.x * 128;
    const size_t CN = (size_t)CC * NPIX;
    const short* W = wob + (ch0 < 256 ? 0 : 65536) + (size_t)(ch0 & 255) * 256;
    const short* Y = (ch0 < 256 ? Y1b : Y2b) + (size_t)b * CN + (size_t)pix0 * 256;
    const float* bias = ch0 < 256 ? b_o1 : b_o2;

    f32x16 acc[2][2] = {};
    mfma_core_single(W, Y, acc);

    const int t = threadIdx.x, lane = t & 63, w = t >> 6;
    const int l31 = lane & 31, l5 = lane >> 5;
    const int aq = (w & 1) * 64, bq = (w >> 1) * 64;
#pragma unroll
    for (int s = 0; s < 2; s++)
#pragma unroll
        for (int u = 0; u < 2; u++)
#pragma unroll
            for (int r = 0; r < 16; r++) {
                int ch = ch0 + aq + s * 32 + cdrow(r, l5);
                int pix = pix0 + bq + u * 32 + l31;
                int chm = ch & 255;
                float v = acc[s][u][r] + bias[chm] +
                          x[((size_t)b * CC + chm) * NPIX + pix];
                out[((size_t)b * 2 * CC + ch) * NPIX + pix] = fmaxf(v, 0.0f);
            }
}

// ---------------- softmax stats ----------------

__global__ __launch_bounds__(256) void rowstats_kernel(
    const float* __restrict__ S, float* __restrict__ rowm, float* __restrict__ rowli)
{
    int n = blockIdx.x;
    const float* r = S + (size_t)n * NPIX;
    int t = threadIdx.x;
    float m = -1e30f, l = 0.0f;
    for (int i = t; i < NPIX; i += 256) {
        float v = r[i];
        float mn = fmaxf(m, v);
        l = l * __expf(m - mn) + __expf(v - mn);
        m = mn;
    }
    for (int off = 32; off; off >>= 1) {
        float m2 = __shfl_xor(m, off, 64);
        float l2 = __shfl_xor(l, off, 64);
        float mn = fmaxf(m, m2);
        l = l * __expf(m - mn) + l2 * __expf(m2 - mn);
        m = mn;
    }
    __shared__ float sm[4], sl[4];
    int w = t >> 6;
    if ((t & 63) == 0) { sm[w] = m; sl[w] = l; }
    __syncthreads();
    if (t == 0) {
        m = sm[0]; l = sl[0];
        for (int i = 1; i < 4; i++) {
            float mn = fmaxf(m, sm[i]);
            l = l * __expf(m - mn) + sl[i] * __expf(sm[i] - mn);
            m = mn;
        }
        rowm[n]  = m;
        rowli[n] = 1.0f / l;
    }
}

__global__ __launch_bounds__(256) void colstats1_kernel(
    const float* __restrict__ S, float* __restrict__ pm, float* __restrict__ pl)
{
    int col = blockIdx.x * 256 + threadIdx.x;
    int r0  = blockIdx.y * 128;
    float m = -1e30f, l = 0.0f;
    for (int r = 0; r < 128; r++) {
        float v = S[(size_t)(r0 + r) * NPIX + col];
        float mn = fmaxf(m, v);
        l = l * __expf(m - mn) + __expf(v - mn);
        m = mn;
    }
    pm[(size_t)blockIdx.y * NPIX + col] = m;
    pl[(size_t)blockIdx.y * NPIX + col] = l;
}

__global__ __launch_bounds__(256) void colstats2_kernel(
    const float* __restrict__ pm, const float* __restrict__ pl,
    float* __restrict__ cm, float* __restrict__ cli)
{
    int col = blockIdx.x * 256 + threadIdx.x;
    float m = -1e30f, l = 0.0f;
    for (int i = 0; i < 32; i++) {
        float m2 = pm[(size_t)i * NPIX + col];
        float l2 = pl[(size_t)i * NPIX + col];
        float mn = fmaxf(m, m2);
        l = l * __expf(m - mn) + l2 * __expf(m2 - mn);
        m = mn;
    }
    cm[col]  = m;
    cli[col] = 1.0f / l;
}

// ---------------- Y = softmax(S) @ V (bf16 MFMA) ----------------
// grid (4, 64, 2); outputs bf16 Y directly.
__global__ __launch_bounds__(256) void ysoft_mfma(
    const float* __restrict__ S, const short* __restrict__ Vt,
    const float* __restrict__ rowm, const float* __restrict__ rowli,
    const float* __restrict__ colm, const float* __restrict__ colli,
    short* __restrict__ Y1b, short* __restrict__ Y2b)
{
    __shared__ short Pa[64 * AST];
    __shared__ short Vb[64 * AST];
    const int mode = blockIdx.z;
    const int c0 = blockIdx.x * 64;
    const int n0 = blockIdx.y * 64;
    const int t = threadIdx.x;
    const int lane = t & 63;
    const int w = t >> 6;
    const int l31 = lane & 31;
    const int l5  = lane >> 5;
    const int nstripe = (w & 1) * 32;
    const int cstripe = (w >> 1) * 32;

    const int pr = t >> 2;
    const int pq = t & 3;

    float sm_n = 0.f, sl_n = 0.f;
    if (mode == 0) { sm_n = rowm[n0 + pr]; sl_n = rowli[n0 + pr]; }

    f32x16 acc = {};

    for (int m0 = 0; m0 < NPIX; m0 += 32) {
        __syncthreads();
        const float* sp = S + (size_t)(n0 + pr) * NPIX + m0 + pq * 8;
        float4 a0 = *(const float4*)sp;
        float4 a1 = *(const float4*)(sp + 4);
        bf16x8 ov;
        if (mode == 0) {
            ov[0] = f2bf(__expf(a0.x - sm_n) * sl_n);
            ov[1] = f2bf(__expf(a0.y - sm_n) * sl_n);
            ov[2] = f2bf(__expf(a0.z - sm_n) * sl_n);
            ov[3] = f2bf(__expf(a0.w - sm_n) * sl_n);
            ov[4] = f2bf(__expf(a1.x - sm_n) * sl_n);
            ov[5] = f2bf(__expf(a1.y - sm_n) * sl_n);
            ov[6] = f2bf(__expf(a1.z - sm_n) * sl_n);
            ov[7] = f2bf(__expf(a1.w - sm_n) * sl_n);
        } else {
            const float* cmp = colm + m0 + pq * 8;
            const float* clp = colli + m0 + pq * 8;
            float4 cm0 = *(const float4*)cmp, cm1 = *(const float4*)(cmp + 4);
            float4 cl0 = *(const float4*)clp, cl1 = *(const float4*)(clp + 4);
            ov[0] = f2bf(__expf(a0.x - cm0.x) * cl0.x);
            ov[1] = f2bf(__expf(a0.y - cm0.y) * cl0.y);
            ov[2] = f2bf(__expf(a0.z - cm0.z) * cl0.z);
            ov[3] = f2bf(__expf(a0.w - cm0.w) * cl0.w);
            ov[4] = f2bf(__expf(a1.x - cm1.x) * cl1.x);
            ov[5] = f2bf(__expf(a1.y - cm1.y) * cl1.y);
            ov[6] = f2bf(__expf(a1.z - cm1.z) * cl1.z);
            ov[7] = f2bf(__expf(a1.w - cm1.w) * cl1.w);
        }
        *(bf16x8*)&Pa[pr * AST + pq * 8] = ov;
        *(bf16x8*)&Vb[pr * AST + pq * 8] =
            *(const bf16x8*)(Vt + (size_t)(c0 + pr) * NPIX + m0 + pq * 8);
        __syncthreads();

        const short* pA = &Pa[(nstripe + l31) * AST + l5 * 8];
        const short* pB = &Vb[(cstripe + l31) * AST + l5 * 8];
        bf16x8 af0 = *(const bf16x8*)pA;
        bf16x8 af1 = *(const bf16x8*)(pA + 16);
        bf16x8 bf0 = *(const bf16x8*)pB;
        bf16x8 bf1 = *(const bf16x8*)(pB + 16);
        acc = __builtin_amdgcn_mfma_f32_32x32x16_bf16(af0, bf0, acc, 0, 0, 0);
        acc = __builtin_amdgcn_mfma_f32_32x32x16_bf16(af1, bf1, acc, 0, 0, 0);
    }

    short* Y = mode ? Y2b : Y1b;
#pragma unroll
    for (int r = 0; r < 16; r++) {
        int row = cdrow(r, l5);
        Y[(size_t)(n0 + nstripe + row) * CC + c0 + cstripe + l31] = f2bf(acc[r]);
    }
}

extern "C" void kernel_launch(void* const* d_in, const int* in_sizes, int n_in,
                              void* d_out, int out_size, void* d_ws, size_t ws_size,
                              hipStream_t stream)
{
    (void)in_sizes; (void)n_in; (void)out_size; (void)ws_size;
    const float* x      = (const float*)d_in[0];
    const float* w_teta = (const float*)d_in[1];
    const float* b_teta = (const float*)d_in[2];
    const float* w_fi   = (const float*)d_in[3];
    const float* b_fi   = (const float*)d_in[4];
    const float* w_gi   = (const float*)d_in[5];
    const float* b_gi   = (const float*)d_in[6];
    const float* w_o1   = (const float*)d_in[7];
    const float* b_o1   = (const float*)d_in[8];
    const float* w_o2   = (const float*)d_in[9];
    const float* b_o2   = (const float*)d_in[10];
    float* out = (float*)d_out;

    const size_t CN = (size_t)CC * NPIX;       // 1M elements
    float* ws    = (float*)d_ws;
    float* S     = ws;                         // 16M floats (64 MB)
    float* x2    = S + (size_t)NPIX * NPIX;    // 4M floats
    float* x3    = x2 + BB * CN;               // 4M floats
    short* x1hi  = (short*)(x3 + BB * CN);     // 4M shorts each
    short* x1lo  = x1hi + BB * CN;
    short* x2thi = x1lo + BB * CN;
    short* x2tlo = x2thi + BB * CN;
    short* Vtb   = x2tlo + BB * CN;
    float* rowm  = (float*)(Vtb + BB * CN);
    float* rowli = rowm + NPIX;
    float* cm    = rowli + NPIX;
    float* cli   = cm + NPIX;
    float* pm    = cli + NPIX;                 // 32*NPIX
    float* pl    = pm + 32 * NPIX;
    short* wphi  = (short*)(pl + 32 * NPIX);   // 3*65536
    short* wplo  = wphi + 3 * 65536;
    short* wob   = wplo + 3 * 65536;           // 2*65536
    // aliases (stream-ordered safe):
    short* xthi = (short*)S;                   // used only before batch loop
    short* xtlo = xthi + BB * CN;
    short* Y1b  = (short*)x3;                  // used only after packVt
    short* Y2b  = Y1b + BB * CN;

    dim3 blk(256);
    pack_w_hilo<<<dim3(64, 3), blk, 0, stream>>>(w_teta, w_fi, w_gi, wphi, wplo);
    pack_w_out<<<dim3(64, 2), blk, 0, stream>>>(w_o1, w_o2, wob);
    pack_t_split<<<dim3(128, 8, 4), blk, 0, stream>>>(x, xthi, xtlo);

    proj_mfma<<<dim3(32, 2, 12), blk, 0, stream>>>(
        wphi, wplo, xthi, xtlo, b_teta, b_fi, b_gi, x1hi, x1lo, x2, x3);

    pack_t_split<<<dim3(128, 8, 4), blk, 0, stream>>>(x2, x2thi, x2tlo);
    packVt_kernel<<<dim3(128, 8, 4), blk, 0, stream>>>(x3, Vtb);

    for (int b = 0; b < BB; b++) {
        scores_mfma<<<dim3(32, 32), blk, 0, stream>>>(
            x1hi + b * CN, x1lo + b * CN, x2thi + b * CN, x2tlo + b * CN, S);
        rowstats_kernel<<<dim3(NPIX), blk, 0, stream>>>(S, rowm, rowli);
        colstats1_kernel<<<dim3(16, 32), blk, 0, stream>>>(S, pm, pl);
        colstats2_kernel<<<dim3(16), blk, 0, stream>>>(pm, pl, cm, cli);
        ysoft_mfma<<<dim3(4, 64, 2), blk, 0, stream>>>(
            S, Vtb + b * CN, rowm, rowli, cm, cli, Y1b + b * CN, Y2b + b * CN);
    }

    out_mfma<<<dim3(32, 4, 4), blk, 0, stream>>>(
        wob, b_o1, b_o2, Y1b, Y2b, x, out);
}

// Round 6
// 760.067 us; speedup vs baseline: 3.9823x; 1.1081x over previous
//
#include <hip/hip_runtime.h>

#define BB   4
#define CC   256
#define NPIX 4096
#define AST2 40    // mfma-core LDS row stride (shorts), 80 B, 16B-aligned
#define YST  72    // ygemm LDS row stride (shorts), 144 B, 16B-aligned

typedef __attribute__((ext_vector_type(8)))  short bf16x8;
typedef __attribute__((ext_vector_type(4)))  short short4v;
typedef __attribute__((ext_vector_type(16))) float f32x16;

__device__ __forceinline__ short f2bf(float f) {
    unsigned u = __float_as_uint(f);
    u = u + 0x7fff + ((u >> 16) & 1);   // RNE
    return (short)(u >> 16);
}
__device__ __forceinline__ float bf2f(short s) {
    return __uint_as_float(((unsigned)(unsigned short)s) << 16);
}
__device__ __forceinline__ void split_bf(float v, short& hi, short& lo) {
    hi = f2bf(v);
    lo = f2bf(v - bf2f(hi));
}
__device__ __forceinline__ int cdrow(int r, int l5) {
    return (r & 3) + 8 * (r >> 2) + 4 * l5;   // verified m74/m101 C/D row map
}

// ---------------------------------------------------------------------------
// hi/lo split-bf16 MFMA core: 128x128 tile, K=256, A/B row-major [row][256].
// ---------------------------------------------------------------------------
__device__ __forceinline__ void mfma_core_hilo(
    const short* __restrict__ Ahi, const short* __restrict__ Alo,
    const short* __restrict__ Bhi, const short* __restrict__ Blo,
    f32x16 acc[2][2])
{
    __shared__ short LAh[128 * AST2], LAl[128 * AST2];
    __shared__ short LBh[128 * AST2], LBl[128 * AST2];
    const int t = threadIdx.x;
    const int lane = t & 63, w = t >> 6;
    const int l31 = lane & 31, l5 = lane >> 5;
    const int nq = (w & 1) * 64, mq = (w >> 1) * 64;
    const int sr = t >> 1;
    const int sk = (t & 1) * 16;
    const size_t gs = (size_t)sr * 256 + sk;
    const int ls = sr * AST2 + sk;

    for (int k0 = 0; k0 < 256; k0 += 32) {
        __syncthreads();
        *(bf16x8*)&LAh[ls]     = *(const bf16x8*)(Ahi + gs + k0);
        *(bf16x8*)&LAh[ls + 8] = *(const bf16x8*)(Ahi + gs + k0 + 8);
        *(bf16x8*)&LAl[ls]     = *(const bf16x8*)(Alo + gs + k0);
        *(bf16x8*)&LAl[ls + 8] = *(const bf16x8*)(Alo + gs + k0 + 8);
        *(bf16x8*)&LBh[ls]     = *(const bf16x8*)(Bhi + gs + k0);
        *(bf16x8*)&LBh[ls + 8] = *(const bf16x8*)(Bhi + gs + k0 + 8);
        *(bf16x8*)&LBl[ls]     = *(const bf16x8*)(Blo + gs + k0);
        *(bf16x8*)&LBl[ls + 8] = *(const bf16x8*)(Blo + gs + k0 + 8);
        __syncthreads();
#pragma unroll
        for (int ks = 0; ks < 2; ks++) {
            bf16x8 ah[2], al[2], bh[2], bl[2];
#pragma unroll
            for (int s = 0; s < 2; s++) {
                int ra = (nq + s * 32 + l31) * AST2 + ks * 16 + l5 * 8;
                int rb = (mq + s * 32 + l31) * AST2 + ks * 16 + l5 * 8;
                ah[s] = *(const bf16x8*)&LAh[ra];
                al[s] = *(const bf16x8*)&LAl[ra];
                bh[s] = *(const bf16x8*)&LBh[rb];
                bl[s] = *(const bf16x8*)&LBl[rb];
            }
#pragma unroll
            for (int s = 0; s < 2; s++)
#pragma unroll
                for (int u = 0; u < 2; u++) {
                    acc[s][u] = __builtin_amdgcn_mfma_f32_32x32x16_bf16(ah[s], bh[u], acc[s][u], 0, 0, 0);
                    acc[s][u] = __builtin_amdgcn_mfma_f32_32x32x16_bf16(ah[s], bl[u], acc[s][u], 0, 0, 0);
                    acc[s][u] = __builtin_amdgcn_mfma_f32_32x32x16_bf16(al[s], bh[u], acc[s][u], 0, 0, 0);
                }
        }
    }
}

// Single-bf16 variant (output GEMM).
__device__ __forceinline__ void mfma_core_single(
    const short* __restrict__ A, const short* __restrict__ B, f32x16 acc[2][2])
{
    __shared__ short LA[128 * AST2], LB[128 * AST2];
    const int t = threadIdx.x;
    const int lane = t & 63, w = t >> 6;
    const int l31 = lane & 31, l5 = lane >> 5;
    const int nq = (w & 1) * 64, mq = (w >> 1) * 64;
    const int sr = t >> 1;
    const int sk = (t & 1) * 16;
    const size_t gs = (size_t)sr * 256 + sk;
    const int ls = sr * AST2 + sk;

    for (int k0 = 0; k0 < 256; k0 += 32) {
        __syncthreads();
        *(bf16x8*)&LA[ls]     = *(const bf16x8*)(A + gs + k0);
        *(bf16x8*)&LA[ls + 8] = *(const bf16x8*)(A + gs + k0 + 8);
        *(bf16x8*)&LB[ls]     = *(const bf16x8*)(B + gs + k0);
        *(bf16x8*)&LB[ls + 8] = *(const bf16x8*)(B + gs + k0 + 8);
        __syncthreads();
#pragma unroll
        for (int ks = 0; ks < 2; ks++) {
            bf16x8 a[2], b[2];
#pragma unroll
            for (int s = 0; s < 2; s++) {
                a[s] = *(const bf16x8*)&LA[(nq + s * 32 + l31) * AST2 + ks * 16 + l5 * 8];
                b[s] = *(const bf16x8*)&LB[(mq + s * 32 + l31) * AST2 + ks * 16 + l5 * 8];
            }
#pragma unroll
            for (int s = 0; s < 2; s++)
#pragma unroll
                for (int u = 0; u < 2; u++)
                    acc[s][u] = __builtin_amdgcn_mfma_f32_32x32x16_bf16(a[s], b[u], acc[s][u], 0, 0, 0);
        }
    }
}

// ---------------- pack kernels ----------------

__global__ __launch_bounds__(256) void pack_w_hilo(
    const float* __restrict__ w0, const float* __restrict__ w1, const float* __restrict__ w2,
    short* __restrict__ whi, short* __restrict__ wlo)
{
    int which = blockIdx.y;
    const float* w = which == 0 ? w0 : which == 1 ? w1 : w2;
    int idx = blockIdx.x * 1024 + threadIdx.x * 4;
    float4 v = *(const float4*)(w + idx);
    short4v h, l;
    short th, tl;
    split_bf(v.x, th, tl); h.x = th; l.x = tl;
    split_bf(v.y, th, tl); h.y = th; l.y = tl;
    split_bf(v.z, th, tl); h.z = th; l.z = tl;
    split_bf(v.w, th, tl); h.w = th; l.w = tl;
    *(short4v*)(whi + which * 65536 + idx) = h;
    *(short4v*)(wlo + which * 65536 + idx) = l;
}

__global__ __launch_bounds__(256) void pack_w_out(
    const float* __restrict__ w1, const float* __restrict__ w2, short* __restrict__ wob)
{
    int which = blockIdx.y;
    const float* w = which == 0 ? w1 : w2;
    int idx = blockIdx.x * 1024 + threadIdx.x * 4;
    float4 v = *(const float4*)(w + idx);
    short4v h;
    h.x = f2bf(v.x); h.y = f2bf(v.y); h.z = f2bf(v.z); h.w = f2bf(v.w);
    *(short4v*)(wob + which * 65536 + idx) = h;
}

// transpose + split: [b][256][4096] fp32 -> [b][4096][256] hi/lo bf16. grid (128,8,4)
__global__ __launch_bounds__(256) void pack_t_split(
    const float* __restrict__ in, short* __restrict__ ohi, short* __restrict__ olo)
{
    __shared__ short Th[32][36], Tl[32][36];
    const int b  = blockIdx.z;
    const int n0 = blockIdx.x * 32;
    const int c0 = blockIdx.y * 32;
    const float* src = in + (size_t)b * CC * NPIX;
    const int t = threadIdx.x;
    const int r = t >> 3, q = t & 7;
    float4 v = *(const float4*)(src + (size_t)(c0 + r) * NPIX + n0 + q * 4);
    short h, l;
    split_bf(v.x, h, l); Th[q * 4 + 0][r] = h; Tl[q * 4 + 0][r] = l;
    split_bf(v.y, h, l); Th[q * 4 + 1][r] = h; Tl[q * 4 + 1][r] = l;
    split_bf(v.z, h, l); Th[q * 4 + 2][r] = h; Tl[q * 4 + 2][r] = l;
    split_bf(v.w, h, l); Th[q * 4 + 3][r] = h; Tl[q * 4 + 3][r] = l;
    __syncthreads();
    short4v oh, ol;
    oh.x = Th[r][q * 4 + 0]; ol.x = Tl[r][q * 4 + 0];
    oh.y = Th[r][q * 4 + 1]; ol.y = Tl[r][q * 4 + 1];
    oh.z = Th[r][q * 4 + 2]; ol.z = Tl[r][q * 4 + 2];
    oh.w = Th[r][q * 4 + 3]; ol.w = Tl[r][q * 4 + 3];
    size_t o = (size_t)b * CC * NPIX + (size_t)(n0 + r) * 256 + c0 + q * 4;
    *(short4v*)(ohi + o) = oh;
    *(short4v*)(olo + o) = ol;
}

// Vt[c][m] = bf16(x3.flat[m*256+c]). grid (128,8,4)
__global__ __launch_bounds__(256) void packVt_kernel(
    const float* __restrict__ x3, short* __restrict__ Vt)
{
    __shared__ short T[32][33];
    const int b  = blockIdx.z;
    const int m0 = blockIdx.x * 32;
    const int c0 = blockIdx.y * 32;
    const float* in = x3 + (size_t)b * CC * NPIX;
    short* out = Vt + (size_t)b * CC * NPIX;
    const int t = threadIdx.x;
    const int r = t >> 3, q = t & 7;
    float4 v = *(const float4*)(in + (size_t)(m0 + r) * CC + c0 + q * 4);
    T[q * 4 + 0][r] = f2bf(v.x);
    T[q * 4 + 1][r] = f2bf(v.y);
    T[q * 4 + 2][r] = f2bf(v.z);
    T[q * 4 + 3][r] = f2bf(v.w);
    __syncthreads();
    short4v o;
    o.x = T[r][q * 4 + 0];
    o.y = T[r][q * 4 + 1];
    o.z = T[r][q * 4 + 2];
    o.w = T[r][q * 4 + 3];
    *(short4v*)(out + (size_t)(c0 + r) * NPIX + m0 + q * 4) = o;
}

// ---------------- GEMM kernels ----------------

// proj. grid (32, 2, 12)
__global__ __launch_bounds__(256) void proj_mfma(
    const short* __restrict__ wphi, const short* __restrict__ wplo,
    const short* __restrict__ xthi, const short* __restrict__ xtlo,
    const float* __restrict__ b_teta, const float* __restrict__ b_fi,
    const float* __restrict__ b_gi,
    short* __restrict__ x1hi, short* __restrict__ x1lo,
    float* __restrict__ x2, float* __restrict__ x3)
{
    const int z = blockIdx.z, p = z >> 2, b = z & 3;
    const int n0 = blockIdx.x * 128, c0 = blockIdx.y * 128;
    const size_t CN = (size_t)CC * NPIX;
    const short* Ah = wphi + p * 65536 + c0 * 256;
    const short* Al = wplo + p * 65536 + c0 * 256;
    const short* Bh = xthi + (size_t)b * CN + (size_t)n0 * 256;
    const short* Bl = xtlo + (size_t)b * CN + (size_t)n0 * 256;
    const float* bias = p == 0 ? b_teta : p == 1 ? b_fi : b_gi;

    f32x16 acc[2][2] = {};
    mfma_core_hilo(Ah, Al, Bh, Bl, acc);

    const int t = threadIdx.x, lane = t & 63, w = t >> 6;
    const int l31 = lane & 31, l5 = lane >> 5;
    const int aq = (w & 1) * 64, bq = (w >> 1) * 64;
#pragma unroll
    for (int s = 0; s < 2; s++)
#pragma unroll
        for (int u = 0; u < 2; u++)
#pragma unroll
            for (int r = 0; r < 16; r++) {
                int c = c0 + aq + s * 32 + cdrow(r, l5);
                int n = n0 + bq + u * 32 + l31;
                float v = acc[s][u][r] + bias[c];
                size_t o = (size_t)b * CN + (size_t)c * NPIX + n;
                if (p == 0) {
                    short h, l; split_bf(v, h, l);
                    x1hi[o] = h; x1lo[o] = l;
                } else if (p == 1) {
                    x2[o] = v;
                } else {
                    x3[o] = v;
                }
            }
}

// scores. grid (32, 32) per batch
__global__ __launch_bounds__(256) void scores_mfma(
    const short* __restrict__ x1hi, const short* __restrict__ x1lo,
    const short* __restrict__ x2thi, const short* __restrict__ x2tlo,
    float* __restrict__ S)
{
    const int m0 = blockIdx.x * 128, n0 = blockIdx.y * 128;
    f32x16 acc[2][2] = {};
    mfma_core_hilo(x1hi + (size_t)n0 * 256, x1lo + (size_t)n0 * 256,
                   x2thi + (size_t)m0 * 256, x2tlo + (size_t)m0 * 256, acc);

    const int t = threadIdx.x, lane = t & 63, w = t >> 6;
    const int l31 = lane & 31, l5 = lane >> 5;
    const int aq = (w & 1) * 64, bq = (w >> 1) * 64;
#pragma unroll
    for (int s = 0; s < 2; s++)
#pragma unroll
        for (int u = 0; u < 2; u++)
#pragma unroll
            for (int r = 0; r < 16; r++) {
                int n = n0 + aq + s * 32 + cdrow(r, l5);
                int m = m0 + bq + u * 32 + l31;
                S[(size_t)n * NPIX + m] = acc[s][u][r];
            }
}

// out: relu(x + bias + W.Y^T), single batch. grid (32, 4)
__global__ __launch_bounds__(256) void out_mfma(
    const short* __restrict__ wob,
    const float* __restrict__ b_o1, const float* __restrict__ b_o2,
    const short* __restrict__ Y1s, const short* __restrict__ Y2s,
    const float* __restrict__ x, float* __restrict__ out, int b)
{
    const int ch0 = blockIdx.y * 128;
    const int pix0 = blockIdx.x * 128;
    const short* W = wob + (ch0 < 256 ? 0 : 65536) + (size_t)(ch0 & 255) * 256;
    const short* Y = (ch0 < 256 ? Y1s : Y2s) + (size_t)pix0 * 256;
    const float* bias = ch0 < 256 ? b_o1 : b_o2;

    f32x16 acc[2][2] = {};
    mfma_core_single(W, Y, acc);

    const int t = threadIdx.x, lane = t & 63, w = t >> 6;
    const int l31 = lane & 31, l5 = lane >> 5;
    const int aq = (w & 1) * 64, bq = (w >> 1) * 64;
#pragma unroll
    for (int s = 0; s < 2; s++)
#pragma unroll
        for (int u = 0; u < 2; u++)
#pragma unroll
            for (int r = 0; r < 16; r++) {
                int ch = ch0 + aq + s * 32 + cdrow(r, l5);
                int pix = pix0 + bq + u * 32 + l31;
                int chm = ch & 255;
                float v = acc[s][u][r] + bias[chm] +
                          x[((size_t)b * CC + chm) * NPIX + pix];
                out[((size_t)b * 2 * CC + ch) * NPIX + pix] = fmaxf(v, 0.0f);
            }
}

// ---------------- softmax stats ----------------

__global__ __launch_bounds__(256) void rowstats_kernel(
    const float* __restrict__ S, float* __restrict__ rowm, float* __restrict__ rowli)
{
    int n = blockIdx.x;
    const float* r = S + (size_t)n * NPIX;
    int t = threadIdx.x;
    float m = -1e30f, l = 0.0f;
    for (int i = t; i < NPIX; i += 256) {
        float v = r[i];
        float mn = fmaxf(m, v);
        l = l * __expf(m - mn) + __expf(v - mn);
        m = mn;
    }
    for (int off = 32; off; off >>= 1) {
        float m2 = __shfl_xor(m, off, 64);
        float l2 = __shfl_xor(l, off, 64);
        float mn = fmaxf(m, m2);
        l = l * __expf(m - mn) + l2 * __expf(m2 - mn);
        m = mn;
    }
    __shared__ float sm[4], sl[4];
    int w = t >> 6;
    if ((t & 63) == 0) { sm[w] = m; sl[w] = l; }
    __syncthreads();
    if (t == 0) {
        m = sm[0]; l = sl[0];
        for (int i = 1; i < 4; i++) {
            float mn = fmaxf(m, sm[i]);
            l = l * __expf(m - mn) + sl[i] * __expf(sm[i] - mn);
            m = mn;
        }
        rowm[n]  = m;
        rowli[n] = 1.0f / l;
    }
}

__global__ __launch_bounds__(256) void colstats1_kernel(
    const float* __restrict__ S, float* __restrict__ pm, float* __restrict__ pl)
{
    int col = blockIdx.x * 256 + threadIdx.x;
    int r0  = blockIdx.y * 128;
    float m = -1e30f, l = 0.0f;
    for (int r = 0; r < 128; r++) {
        float v = S[(size_t)(r0 + r) * NPIX + col];
        float mn = fmaxf(m, v);
        l = l * __expf(m - mn) + __expf(v - mn);
        m = mn;
    }
    pm[(size_t)blockIdx.y * NPIX + col] = m;
    pl[(size_t)blockIdx.y * NPIX + col] = l;
}

__global__ __launch_bounds__(256) void colstats2_kernel(
    const float* __restrict__ pm, const float* __restrict__ pl,
    float* __restrict__ cm, float* __restrict__ cli)
{
    int col = blockIdx.x * 256 + threadIdx.x;
    float m = -1e30f, l = 0.0f;
    for (int i = 0; i < 32; i++) {
        float m2 = pm[(size_t)i * NPIX + col];
        float l2 = pl[(size_t)i * NPIX + col];
        float mn = fmaxf(m, m2);
        l = l * __expf(m - mn) + l2 * __expf(m2 - mn);
        m = mn;
    }
    cm[col]  = m;
    cli[col] = 1.0f / l;
}

// ---------------- P materialization ----------------
// One block per S row (2048 rows per launch). Writes P1 (row softmax) and
// P2 (col softmax) bf16 [row][m] for this half. S read via absolute row.
__global__ __launch_bounds__(256) void expP_kernel(
    const float* __restrict__ S, int n_off,
    const float* __restrict__ rowm, const float* __restrict__ rowli,
    const float* __restrict__ colm, const float* __restrict__ colli,
    short* __restrict__ P1, short* __restrict__ P2)
{
    const int row = blockIdx.x;
    const int n = n_off + row;
    const float rm = rowm[n], rl = rowli[n];
    const float* sp = S + (size_t)n * NPIX;
    short* p1 = P1 + (size_t)row * NPIX;
    short* p2 = P2 + (size_t)row * NPIX;
    const int t = threadIdx.x;
#pragma unroll
    for (int i = 0; i < 4; i++) {
        int idx = (i * 256 + t) * 4;
        float4 s4  = *(const float4*)(sp + idx);
        float4 cm4 = *(const float4*)(colm + idx);
        float4 cl4 = *(const float4*)(colli + idx);
        short4v a, bvv;
        a.x = f2bf(__expf(s4.x - rm) * rl);
        a.y = f2bf(__expf(s4.y - rm) * rl);
        a.z = f2bf(__expf(s4.z - rm) * rl);
        a.w = f2bf(__expf(s4.w - rm) * rl);
        bvv.x = f2bf(__expf(s4.x - cm4.x) * cl4.x);
        bvv.y = f2bf(__expf(s4.y - cm4.y) * cl4.y);
        bvv.z = f2bf(__expf(s4.z - cm4.z) * cl4.z);
        bvv.w = f2bf(__expf(s4.w - cm4.w) * cl4.w);
        *(short4v*)(p1 + idx) = a;
        *(short4v*)(p2 + idx) = bvv;
    }
}

// ---------------- Y = P @ Vt^T (deep-K bf16 GEMM) ----------------
// 64n x 64c tiles, K=4096 in steps of 64; grid (4 cT, 64 nT, 2 mode).
// P split in two row-halves (a: rows 0..2047, b: rows 2048..4095).
__global__ __launch_bounds__(256) void ygemm_kernel(
    const short* __restrict__ P1a, const short* __restrict__ P1b,
    const short* __restrict__ P2a, const short* __restrict__ P2b,
    const short* __restrict__ Vt,
    short* __restrict__ Y1s, short* __restrict__ Y2s)
{
    __shared__ short LA[64 * YST], LB[64 * YST];
    const int mode = blockIdx.z;
    const int n0 = blockIdx.y * 64;
    const int c0 = blockIdx.x * 64;
    const short* Pa_ = mode ? P2a : P1a;
    const short* Pb_ = mode ? P2b : P1b;
    const short* A = (n0 < 2048) ? (Pa_ + (size_t)n0 * NPIX)
                                 : (Pb_ + (size_t)(n0 - 2048) * NPIX);
    const short* B = Vt + (size_t)c0 * NPIX;

    const int t = threadIdx.x, lane = t & 63, w = t >> 6;
    const int l31 = lane & 31, l5 = lane >> 5;
    const int nst = (w & 1) * 32, cst = (w >> 1) * 32;
    const int sr = t >> 3;            // staging row 0..31 (and +32)
    const int sk = (t & 7) * 8;       // staging k offset (shorts)

    f32x16 acc = {};
    for (int k0 = 0; k0 < NPIX; k0 += 64) {
        __syncthreads();
        *(bf16x8*)&LA[sr * YST + sk] =
            *(const bf16x8*)(A + (size_t)sr * NPIX + k0 + sk);
        *(bf16x8*)&LA[(32 + sr) * YST + sk] =
            *(const bf16x8*)(A + (size_t)(32 + sr) * NPIX + k0 + sk);
        *(bf16x8*)&LB[sr * YST + sk] =
            *(const bf16x8*)(B + (size_t)sr * NPIX + k0 + sk);
        *(bf16x8*)&LB[(32 + sr) * YST + sk] =
            *(const bf16x8*)(B + (size_t)(32 + sr) * NPIX + k0 + sk);
        __syncthreads();
#pragma unroll
        for (int kc = 0; kc < 4; kc++) {
            bf16x8 af = *(const bf16x8*)&LA[(nst + l31) * YST + kc * 16 + l5 * 8];
            bf16x8 bf = *(const bf16x8*)&LB[(cst + l31) * YST + kc * 16 + l5 * 8];
            acc = __builtin_amdgcn_mfma_f32_32x32x16_bf16(af, bf, acc, 0, 0, 0);
        }
    }
    short* Y = mode ? Y2s : Y1s;
#pragma unroll
    for (int r = 0; r < 16; r++) {
        int rr = cdrow(r, l5);
        Y[(size_t)(n0 + nst + rr) * CC + c0 + cst + l31] = f2bf(acc[r]);
    }
}

extern "C" void kernel_launch(void* const* d_in, const int* in_sizes, int n_in,
                              void* d_out, int out_size, void* d_ws, size_t ws_size,
                              hipStream_t stream)
{
    (void)in_sizes; (void)n_in; (void)out_size; (void)ws_size;
    const float* x      = (const float*)d_in[0];
    const float* w_teta = (const float*)d_in[1];
    const float* b_teta = (const float*)d_in[2];
    const float* w_fi   = (const float*)d_in[3];
    const float* b_fi   = (const float*)d_in[4];
    const float* w_gi   = (const float*)d_in[5];
    const float* b_gi   = (const float*)d_in[6];
    const float* w_o1   = (const float*)d_in[7];
    const float* b_o1   = (const float*)d_in[8];
    const float* w_o2   = (const float*)d_in[9];
    const float* b_o2   = (const float*)d_in[10];
    float* out = (float*)d_out;

    const size_t CN = (size_t)CC * NPIX;       // 1M elements
    const size_t HALF = (size_t)2048 * NPIX;   // 8M shorts = 16 MB
    float* ws    = (float*)d_ws;
    // --- persistent regions ---
    float* S     = ws;                          // 64 MB
    short* Pfr   = (short*)(S + (size_t)NPIX * NPIX);  // 32 MB (P1a+P2a)
    short* x1hi  = Pfr + 2 * HALF;              // 8 MB each
    short* x1lo  = x1hi + BB * CN;
    short* x2thi = x1lo + BB * CN;
    short* x2tlo = x2thi + BB * CN;
    short* Vtb   = x2tlo + BB * CN;             // 8 MB
    short* Y1s   = Vtb + BB * CN;               // 2 MB (single batch)
    short* Y2s   = Y1s + CN;                    // 2 MB
    float* rowm  = (float*)(Y2s + CN);
    float* rowli = rowm + NPIX;
    float* cm    = rowli + NPIX;
    float* cli   = cm + NPIX;
    float* pm    = cli + NPIX;                  // 32*NPIX
    float* pl    = pm + 32 * NPIX;
    short* wphi  = (short*)(pl + 32 * NPIX);    // 3*65536
    short* wplo  = wphi + 3 * 65536;
    short* wob   = wplo + 3 * 65536;            // 2*65536
    // --- aliases ---
    short* xthi = (short*)S;                    // pre-phase only (16 MB in S)
    short* xtlo = xthi + BB * CN;
    float* x2   = (float*)Pfr;                  // pre-phase only (16 MB)
    float* x3   = x2 + BB * CN;                 // pre-phase only (16 MB)
    // P halves: a-halves in Pfr, b-halves overwrite S's first 32 MB
    short* P1a = Pfr;
    short* P2a = Pfr + HALF;
    short* P1b = (short*)S;
    short* P2b = (short*)S + HALF;

    dim3 blk(256);
    pack_w_hilo<<<dim3(64, 3), blk, 0, stream>>>(w_teta, w_fi, w_gi, wphi, wplo);
    pack_w_out<<<dim3(64, 2), blk, 0, stream>>>(w_o1, w_o2, wob);
    pack_t_split<<<dim3(128, 8, 4), blk, 0, stream>>>(x, xthi, xtlo);

    proj_mfma<<<dim3(32, 2, 12), blk, 0, stream>>>(
        wphi, wplo, xthi, xtlo, b_teta, b_fi, b_gi, x1hi, x1lo, x2, x3);

    pack_t_split<<<dim3(128, 8, 4), blk, 0, stream>>>(x2, x2thi, x2tlo);
    packVt_kernel<<<dim3(128, 8, 4), blk, 0, stream>>>(x3, Vtb);

    for (int b = 0; b < BB; b++) {
        scores_mfma<<<dim3(32, 32), blk, 0, stream>>>(
            x1hi + b * CN, x1lo + b * CN, x2thi + b * CN, x2tlo + b * CN, S);
        rowstats_kernel<<<dim3(NPIX), blk, 0, stream>>>(S, rowm, rowli);
        colstats1_kernel<<<dim3(16, 32), blk, 0, stream>>>(S, pm, pl);
        colstats2_kernel<<<dim3(16), blk, 0, stream>>>(pm, pl, cm, cli);
        // half 1: rows [0,2048) -> Pfr ; half 2: rows [2048,4096) -> S base
        expP_kernel<<<dim3(2048), blk, 0, stream>>>(S, 0, rowm, rowli, cm, cli, P1a, P2a);
        expP_kernel<<<dim3(2048), blk, 0, stream>>>(S, 2048, rowm, rowli, cm, cli, P1b, P2b);
        ygemm_kernel<<<dim3(4, 64, 2), blk, 0, stream>>>(
            P1a, P1b, P2a, P2b, Vtb + b * CN, Y1s, Y2s);
        out_mfma<<<dim3(32, 4), blk, 0, stream>>>(
            wob, b_o1, b_o2, Y1s, Y2s, x, out, b);
    }
}